// Round 6
// baseline (667.567 us; speedup 1.0000x reference)
//
#include <hip/hip_runtime.h>
#include <stdint.h>
#include <math.h>

typedef unsigned short u16;
typedef short bf16x8 __attribute__((ext_vector_type(8)));
typedef float f32x4 __attribute__((ext_vector_type(4)));

#define MFMA16x16x32(a,b,c) __builtin_amdgcn_mfma_f32_16x16x32_bf16((a),(b),(c),0,0,0)

typedef __attribute__((address_space(3))) void as3_void;
typedef const __attribute__((address_space(1))) void as1_void;

__device__ __forceinline__ void g2l16(const void* g, void* l){
#if __has_builtin(__builtin_amdgcn_global_load_lds)
  __builtin_amdgcn_global_load_lds((as1_void*)g, (as3_void*)l, 16, 0, 0);
#else
  *(int4*)l = *(const int4*)g;
#endif
}

__device__ __forceinline__ u16 f2bf(float f){
  uint32_t u = __builtin_bit_cast(uint32_t, f);
  u += 0x7fffu + ((u >> 16) & 1u);
  return (u16)(u >> 16);
}
__device__ __forceinline__ float bf2f(u16 h){
  uint32_t u = ((uint32_t)h) << 16;
  return __builtin_bit_cast(float, u);
}
__device__ __forceinline__ void unpack8(int4 v, float* o){
  uint32_t w0=(uint32_t)v.x, w1=(uint32_t)v.y, w2=(uint32_t)v.z, w3=(uint32_t)v.w;
  o[0]=__builtin_bit_cast(float, w0<<16); o[1]=__builtin_bit_cast(float, w0&0xffff0000u);
  o[2]=__builtin_bit_cast(float, w1<<16); o[3]=__builtin_bit_cast(float, w1&0xffff0000u);
  o[4]=__builtin_bit_cast(float, w2<<16); o[5]=__builtin_bit_cast(float, w2&0xffff0000u);
  o[6]=__builtin_bit_cast(float, w3<<16); o[7]=__builtin_bit_cast(float, w3&0xffff0000u);
}
__device__ __forceinline__ int iclampi(int v,int lo,int hi){ return v<lo?lo:(v>hi?hi:v); }

// ---------------------------------------------------------------------------
// Weights frag-packed per K-tile-64 chunk (identical layout to round 4).
__global__ void k_repack(const float* __restrict__ w_reset, const float* __restrict__ b_reset,
                         const float* __restrict__ w_update, const float* __restrict__ b_update,
                         const float* __restrict__ w_out, const float* __restrict__ w_offset,
                         const float* __restrict__ w_align,
                         u16* __restrict__ wgate, u16* __restrict__ wout,
                         u16* __restrict__ walign, float* __restrict__ woff,
                         float* __restrict__ biascat){
  int idx = blockIdx.x * 256 + threadIdx.x;
  if (idx < 512*4608){           // gate: BN=256, nb in {0,1}
    int e = idx & 7, j = (idx >> 3) & 2047, chunk = idx >> 14;
    int nb = chunk & 1, kk = chunk >> 1;
    int l = j & 15, q = (j >> 4) & 3, t16 = (j >> 6) & 15, ks2 = j >> 10;
    int n = nb*256 + t16*16 + l;
    int tap = kk >> 3, ksin = kk & 7;
    int c = ksin*64 + ks2*32 + q*8 + e;
    int ky = tap/3, kx = tap%3;
    float v = (n < 256) ? w_update[((n*512 + c)*3 + ky)*3 + kx]
                        : w_reset[(((n-256)*512 + c)*3 + ky)*3 + kx];
    wgate[idx] = f2bf(v);
  }
  if (idx < 256*4608){           // out: BN=128, nb in {0,1}
    int e = idx & 7, j = (idx >> 3) & 1023, chunk = idx >> 13;
    int nb = chunk & 1, kk = chunk >> 1;
    int l = j & 15, q = (j >> 4) & 3, t8 = (j >> 6) & 7, ks2 = j >> 9;
    int n = nb*128 + t8*16 + l;
    int tap = kk >> 3, ksin = kk & 7;
    int c = ksin*64 + ks2*32 + q*8 + e;
    int ky = tap/3, kx = tap%3;
    wout[idx] = f2bf(w_out[((n*512 + c)*3 + ky)*3 + kx]);
  }
  if (idx < 256*2304){           // align (k_deform reads directly)
    int n = idx / 2304, k = idx % 2304;
    int tap = k >> 8, c = k & 255;
    int ky = tap/3, kx = tap%3;
    walign[idx] = f2bf(w_align[((n*256 + c)*3 + ky)*3 + kx]);
  }
  if (idx < 1458) woff[idx] = w_offset[idx] * (1.f/256.f);
  if (idx < 512) biascat[idx] = (idx < 256) ? b_update[idx] : b_reset[idx-256];
}

// ---------------------------------------------------------------------------
// NCHW fp32 -> NHWC bf16.
__global__ __launch_bounds__(256) void k_transform(const float* __restrict__ inputs,
    const float* __restrict__ in_state, u16* __restrict__ stacked,
    u16* __restrict__ stacked2, u16* __restrict__ x2pad){
  __shared__ u16 t1[64*264];
  __shared__ u16 t2[64*264];
  int tid = threadIdx.x, bh = blockIdx.x;
  int b = bh >> 6, h = bh & 63;
  int w = tid & 63, cq = tid >> 6;
  for (int i = 0; i < 64; ++i){
    int c = i*4 + cq;
    int gi = ((b*256 + c)*64 + h)*64 + w;
    t1[w*264 + c] = f2bf(inputs[gi]);
    t2[w*264 + c] = f2bf(in_state[gi]);
  }
  __syncthreads();
  int px = tid >> 2, cg = tid & 3;
#pragma unroll
  for (int u = 0; u < 8; ++u){
    int c = cg*64 + u*8;
    int4 v1 = *(const int4*)(t1 + px*264 + c);
    int4 v2 = *(const int4*)(t2 + px*264 + c);
    *(int4*)(stacked  + (((b*66 + h+1)*66) + (px+1))*512 + c) = v1;
    *(int4*)(stacked2 + (((b*66 + h+1)*66) + (px+1))*512 + c) = v1;
    *(int4*)(x2pad    + (((b*72 + h+4)*72) + (px+4))*256 + c) = v2;
  }
}

// ---------------------------------------------------------------------------
// Correlation as masked local GEMM.
__global__ __launch_bounds__(256) void k_corr(const u16* __restrict__ stacked,
    const u16* __restrict__ x2pad, float* __restrict__ corr){
  __shared__ u16 lA[8192];
  __shared__ u16 lB[32768];
  int tid = threadIdx.x, idx = blockIdx.x;
  int b = idx >> 6, ty = (idx >> 3) & 7, tx = idx & 7;
  int h0 = ty*8, w0 = tx*8;
  int wave = tid >> 6, lane = tid & 63, l15 = lane & 15, quad = lane >> 4;
  f32x4 acc[4][4];
#pragma unroll
  for (int i=0;i<4;i++)
#pragma unroll
    for (int j=0;j<4;j++){ f32x4 z = {0.f,0.f,0.f,0.f}; acc[i][j] = z; }

  for (int s = 0; s < 2; ++s){
#pragma unroll
    for (int i = 0; i < 4; ++i){
      int j = tid + i*256;
      int ml = j & 15, q = (j>>4)&3, mt = (j>>6)&3, ks = j >> 8;
      int px = mt*16 + ml, py = px >> 3, pxx = px & 7;
      const u16* g = stacked + (((b*66 + h0+py+1)*66) + (w0+pxx+1))*512 + s*128 + ks*32 + q*8;
      g2l16(g, lA + j*8);
    }
#pragma unroll
    for (int i = 0; i < 16; ++i){
      int j = tid + i*256;
      int nl = j & 15, q = (j>>4)&3, nt = (j>>6)&15, ks = j >> 10;
      int qp = nt*16 + nl, qy = qp >> 4, qx = qp & 15;
      const u16* g = x2pad + (((b*72 + h0+qy)*72) + (w0+qx))*256 + s*128 + ks*32 + q*8;
      g2l16(g, lB + j*8);
    }
    __syncthreads();
#pragma unroll
    for (int ks = 0; ks < 4; ++ks){
      bf16x8 bv[4];
#pragma unroll
      for (int ni=0; ni<4; ++ni){
        int nt = wave*4 + ni;
        bv[ni] = *(const bf16x8*)(lB + (((ks*16 + nt)*4 + quad)*16 + l15)*8);
      }
#pragma unroll
      for (int mi=0; mi<4; ++mi){
        bf16x8 av = *(const bf16x8*)(lA + (((ks*4 + mi)*4 + quad)*16 + l15)*8);
#pragma unroll
        for (int ni=0; ni<4; ++ni) acc[mi][ni] = MFMA16x16x32(av, bv[ni], acc[mi][ni]);
      }
    }
    __syncthreads();
  }
#pragma unroll
  for (int mi=0; mi<4; ++mi){
#pragma unroll
    for (int ni=0; ni<4; ++ni){
      int n = wave*64 + ni*16 + l15;
      int qy = n >> 4, qx = n & 15;
#pragma unroll
      for (int r=0; r<4; ++r){
        int m = mi*16 + quad*4 + r;
        int py = m >> 3, pxx = m & 7;
        int dy = qy - py, dx = qx - pxx;
        if ((unsigned)dy <= 8u && (unsigned)dx <= 8u)
          corr[(((b*64 + h0+py)*64) + (w0+pxx))*81 + dy*9 + dx] = acc[mi][ni][r];
      }
    }
  }
}

// ---------------------------------------------------------------------------
__global__ __launch_bounds__(256) void k_offset(const float* __restrict__ corr,
    const float* __restrict__ woff, float* __restrict__ offs){
  __shared__ float lc[32*84];
  __shared__ float lw[18*84];
  int tid = threadIdx.x, blk = blockIdx.x;
  int row = blk >> 1, half = blk & 1;
  int base = row*5184 + half*32*81;
  for (int i = tid; i < 32*81; i += 256){
    int px = i / 81, d = i % 81;
    lc[px*84 + d] = corr[base + i];
  }
  for (int i = tid; i < 18*84; i += 256){
    int o = i / 84, d = i % 84;
    if (d < 81) lw[i] = woff[o*81 + d];
  }
  __syncthreads();
  int px = tid & 31, og = tid >> 5;
  for (int o = og; o < 18; o += 8){
    float s = 0.f;
#pragma unroll
    for (int dd = 0; dd < 20; ++dd){
      float4 a = *(const float4*)(lc + px*84 + dd*4);
      float4 wv = *(const float4*)(lw + o*84 + dd*4);
      s += a.x*wv.x + a.y*wv.y + a.z*wv.z + a.w*wv.w;
    }
    s += lc[px*84 + 80] * lw[o*84 + 80];
    offs[(row*64 + half*32 + px)*18 + o] = s;
  }
}

// ---------------------------------------------------------------------------
// Deformable conv (unchanged).
__global__ __launch_bounds__(256) void k_deform(const u16* __restrict__ x2pad,
    const float* __restrict__ offs, const u16* __restrict__ walign,
    u16* __restrict__ stacked){
  __shared__ u16 lA[16384];
  int tid = threadIdx.x, bh = blockIdx.x;
  int b = bh >> 6, h = bh & 63;
  int wave = tid >> 6, lane = tid & 63, l15 = lane & 15, quad = lane >> 4;
  int px = tid >> 2, cg = tid & 3;
  int mt_s = px >> 4, ml_s = px & 15;
  f32x4 acc[4][4];
#pragma unroll
  for (int i=0;i<4;i++)
#pragma unroll
    for (int j=0;j<4;j++){ f32x4 z = {0.f,0.f,0.f,0.f}; acc[i][j] = z; }

  for (int tap = 0; tap < 9; ++tap){
    int ky = tap/3, kx = tap%3;
    float offy = offs[(bh*64 + px)*18 + 2*tap];
    float offx = offs[(bh*64 + px)*18 + 2*tap + 1];
    float y = (float)(h + ky - 1) + offy;
    float x = (float)(px + kx - 1) + offx;
    float y0f = floorf(y), x0f = floorf(x);
    float wy1 = y - y0f, wx1 = x - x0f;
    float wy0 = 1.f - wy1, wx0 = 1.f - wx1;
    int iy0 = iclampi((int)y0f, -4, 67), ix0 = iclampi((int)x0f, -4, 67);
    int iy1 = iclampi((int)y0f + 1, -4, 67), ix1 = iclampi((int)x0f + 1, -4, 67);
    const u16* p00 = x2pad + (((b*72 + iy0+4)*72) + (ix0+4))*256 + cg*64;
    const u16* p01 = x2pad + (((b*72 + iy0+4)*72) + (ix1+4))*256 + cg*64;
    const u16* p10 = x2pad + (((b*72 + iy1+4)*72) + (ix0+4))*256 + cg*64;
    const u16* p11 = x2pad + (((b*72 + iy1+4)*72) + (ix1+4))*256 + cg*64;
    float w00 = wy0*wx0, w01 = wy0*wx1, w10 = wy1*wx0, w11 = wy1*wx1;
#pragma unroll
    for (int u = 0; u < 8; ++u){
      int4 v00 = *(const int4*)(p00 + u*8);
      int4 v01 = *(const int4*)(p01 + u*8);
      int4 v10 = *(const int4*)(p10 + u*8);
      int4 v11 = *(const int4*)(p11 + u*8);
      float a00[8], a01[8], a10[8], a11[8];
      unpack8(v00,a00); unpack8(v01,a01); unpack8(v10,a10); unpack8(v11,a11);
      union { u16 h2[8]; int4 v; } R;
#pragma unroll
      for (int jj = 0; jj < 8; ++jj)
        R.h2[jj] = f2bf(w00*a00[jj] + w01*a01[jj] + w10*a10[jj] + w11*a11[jj]);
      int ch = cg*64 + u*8;
      int ks = ch >> 5, q = (ch >> 3) & 3;
      *(int4*)(lA + (((ks*4 + mt_s)*4 + q)*16 + ml_s)*8) = R.v;
    }
    __syncthreads();
#pragma unroll
    for (int ks = 0; ks < 8; ++ks){
      bf16x8 bv[4];
#pragma unroll
      for (int ni=0; ni<4; ++ni){
        int n = wave*64 + ni*16 + l15;
        bv[ni] = *(const bf16x8*)(walign + n*2304 + tap*256 + ks*32 + quad*8);
      }
#pragma unroll
      for (int mi=0; mi<4; ++mi){
        bf16x8 av = *(const bf16x8*)(lA + (((ks*4 + mi)*4 + quad)*16 + l15)*8);
#pragma unroll
        for (int ni=0; ni<4; ++ni) acc[mi][ni] = MFMA16x16x32(av, bv[ni], acc[mi][ni]);
      }
    }
    __syncthreads();
  }
#pragma unroll
  for (int mi=0; mi<4; ++mi){
#pragma unroll
    for (int ni=0; ni<4; ++ni){
      int n = wave*64 + ni*16 + l15;
#pragma unroll
      for (int r=0; r<4; ++r){
        int m = mi*16 + quad*4 + r;
        stacked[(((b*66 + h+1)*66) + (m+1))*512 + 256 + n] = f2bf(acc[mi][ni][r]);
      }
    }
  }
}

// ---------------------------------------------------------------------------
// Staging: split by ks2 (K-half). Slot j = const | tid -> LDS dest is
// wave-uniform base + lane*16 (global_load_lds requirement).
__device__ __forceinline__ void stageA_k(u16* __restrict__ dst,
    const u16* __restrict__ in, int b, int h0, int kk, int ks2, int tid){
  int tap = kk >> 3, ksin = kk & 7;
  int ky = tap/3, kx = tap - ky*3;
  const u16* abase = in + ((b*66 + h0 + ky)*66 + kx)*512 + ksin*64 + ks2*32;
#pragma unroll
  for (int i = 0; i < 2; ++i){
    int j = (ks2<<10) | (i<<9) | tid;
    int l = j & 15, q = (j >> 4) & 3, t16 = (j >> 6) & 15;
    int px = t16*16 + l, r = px >> 6, w = px & 63;
    g2l16(abase + (r*66 + w)*512 + q*8, dst + j*8);
  }
}
__device__ __forceinline__ void stageB16_k(u16* __restrict__ dst,
    const u16* __restrict__ wts, int nb, int kk, int ks2, int tid){
  const u16* wch = wts + (size_t)(kk*2 + nb) * 16384;
#pragma unroll
  for (int i = 0; i < 2; ++i){
    int j = (ks2<<10) | (i<<9) | tid;
    g2l16(wch + j*8, dst + j*8);
  }
}
__device__ __forceinline__ void stageB8_k(u16* __restrict__ dst,
    const u16* __restrict__ wts, int nb, int kk, int ks2, int tid){
  const u16* wch = wts + (size_t)(kk*2 + nb) * 8192;
  int j = (ks2<<9) | tid;
  g2l16(wch + j*8, dst + j*8);
}

// ---------------------------------------------------------------------------
// Phase skeleton (no per-phase barrier): next-phase operand ds_reads, then
// staging (p0 only), then fenced MFMA cluster. Cross-wave sync happens ONCE
// per K-tile (end-p2) via __syncthreads() (vmcnt0+lgkm0+barrier): vmcnt
// retires this tile's staged loads (issued 2 phases earlier, latency hidden);
// lgkm keeps a wave from passing the barrier with cur-reads in flight.
// Between barriers waves slip out of lockstep, overlapping one wave's LDS
// bursts with another's MFMA cluster (setprio biases the MFMA wave).
#define PH16(CMH, AVC, BVC, AVN, BVN, LOADB, RA, RB, NMH, NK2, STG, EPI) do { \
  _Pragma("unroll") \
  for (int m4_=0;m4_<4;++m4_) \
    AVN[m4_] = *(const bf16x8*)((const u16*)(RA) + ((((NK2)*16 + wm*8 + (NMH)*4 + m4_)*4 + quad)*16 + l15)*8); \
  if (LOADB){ \
    _Pragma("unroll") \
    for (int ni_=0;ni_<4;++ni_) \
      BVN[ni_] = *(const bf16x8*)((const u16*)(RB) + ((((NK2)*16 + wn*4 + ni_)*4 + quad)*16 + l15)*8); \
  } \
  STG; \
  __builtin_amdgcn_sched_barrier(0); \
  __builtin_amdgcn_s_setprio(1); \
  _Pragma("unroll") \
  for (int m4_=0;m4_<4;++m4_){ \
    _Pragma("unroll") \
    for (int ni_=0;ni_<4;++ni_) \
      acc[(CMH)*4+m4_][ni_] = MFMA16x16x32(AVC[m4_], BVC[ni_], acc[(CMH)*4+m4_][ni_]); \
  } \
  __builtin_amdgcn_s_setprio(0); \
  __builtin_amdgcn_sched_barrier(0); \
  EPI; \
} while(0)

// NT=8 quarter-phase: 4 av x 2 bv = 8 MFMA.
#define PH8Q(CMH, AVC, BVC, AVN, BVN, LOADB, RA, RB, NMH, NK2, STG, EPI) do { \
  _Pragma("unroll") \
  for (int m4_=0;m4_<4;++m4_) \
    AVN[m4_] = *(const bf16x8*)((const u16*)(RA) + ((((NK2)*16 + wm*8 + (NMH)*4 + m4_)*4 + quad)*16 + l15)*8); \
  if (LOADB){ \
    _Pragma("unroll") \
    for (int ni_=0;ni_<2;++ni_) \
      BVN[ni_] = *(const bf16x8*)((const u16*)(RB) + ((((NK2)*8 + wn*2 + ni_)*4 + quad)*16 + l15)*8); \
  } \
  STG; \
  __builtin_amdgcn_sched_barrier(0); \
  __builtin_amdgcn_s_setprio(1); \
  _Pragma("unroll") \
  for (int m4_=0;m4_<4;++m4_){ \
    _Pragma("unroll") \
    for (int ni_=0;ni_<2;++ni_) \
      acc[(CMH)*4+m4_][ni_] = MFMA16x16x32(AVC[m4_], BVC[ni_], acc[(CMH)*4+m4_][ni_]); \
  } \
  __builtin_amdgcn_s_setprio(0); \
  __builtin_amdgcn_sched_barrier(0); \
  EPI; \
} while(0)

#define SYNCTILE do { \
  __syncthreads(); \
  __builtin_amdgcn_sched_barrier(0); \
} while(0)

// 3x3 conv, implicit GEMM, 256px x (NT*16)n tile, 8 waves (2M x 4N), BK=64.
// One-phase register lookahead + ONE barrier per K-tile (end-p2).
template<int NT, bool STATS>
__global__ __launch_bounds__(512, 2) void k_conv256(const u16* __restrict__ in,
    const u16* __restrict__ wts, const float* __restrict__ bias,
    u16* __restrict__ outp, float* __restrict__ partials){
  constexpr int NI = NT / 4;
  __shared__ u16 lA[2][16384];      // 256 px x 64 ch per buffer
  __shared__ u16 lB[2][NT*1024];    // (NT*16) n x 64 ch per buffer

  int tid = threadIdx.x, g = blockIdx.x;
  int work = (g & 7) * 32 + (g >> 3);     // bijective XCD swizzle (256 % 8 == 0)
  int nb = work >> 7, mt = work & 127;    // nb-major: 32 works/XCD share B panel
  int b = mt >> 4, h0 = (mt & 15) * 4;
  int wave = tid >> 6, lane = tid & 63, l15 = lane & 15, quad = lane >> 4;
  int wm = wave & 1, wn = wave >> 1;

  f32x4 acc[8][NI];
#pragma unroll
  for (int i=0;i<8;i++)
#pragma unroll
    for (int j=0;j<NI;j++){ f32x4 z = {0.f,0.f,0.f,0.f}; acc[i][j] = z; }

  if constexpr (NT == 16){
    bf16x8 avA[4], avB[4], bvA[4], bvB[4];
    // Prologue: stage tile 0 fully; retire + globalize; read p0 operands.
    stageA_k(&lA[0][0], in, b, h0, 0, 0, tid);
    stageB16_k(&lB[0][0], wts, nb, 0, 0, tid);
    stageA_k(&lA[0][0], in, b, h0, 0, 1, tid);
    stageB16_k(&lB[0][0], wts, nb, 0, 1, tid);
    __syncthreads();
#pragma unroll
    for (int m4_=0;m4_<4;++m4_)
      avA[m4_] = *(const bf16x8*)(&lA[0][0] + (((wm*8 + m4_)*4 + quad)*16 + l15)*8);
#pragma unroll
    for (int ni_=0;ni_<4;++ni_)
      bvA[ni_] = *(const bf16x8*)(&lB[0][0] + (((wn*4 + ni_)*4 + quad)*16 + l15)*8);

#pragma unroll 1
    for (int t = 0; t < 72; ++t){
      int d = t & 1;
      const u16* Acur = &lA[d][0];
      const u16* Bcur = &lB[d][0];
      u16* Anx = &lA[d^1][0];
      u16* Bnx = &lB[d^1][0];
      bool hn = (t < 71);
      int kn = t + 1;
      // p0: MFMA(avA,bvA)->(mh0,k0); rd avB=(mh1,k0)@cur; stage ALL 8 -> nx
      PH16(0, avA, bvA, avB, bvB, 0, Acur, Bcur, 1, 0,
           if (hn){ stageA_k(Anx, in, b, h0, kn, 0, tid);
                    stageB16_k(Bnx, wts, nb, kn, 0, tid);
                    stageA_k(Anx, in, b, h0, kn, 1, tid);
                    stageB16_k(Bnx, wts, nb, kn, 1, tid); }, );
      // p1: MFMA(avB,bvA)->(mh1,k0); rd avA=(mh0,k1)@cur + bvB=(k1)@cur
      PH16(1, avB, bvA, avA, bvB, 1, Acur, Bcur, 0, 1, , );
      // p2: MFMA(avA,bvB)->(mh0,k1); rd avB=(mh1,k1)@cur; then K-tile sync
      PH16(0, avA, bvB, avB, bvA, 0, Acur, Bcur, 1, 1, , SYNCTILE);
      // p3: MFMA(avB,bvB)->(mh1,k1); rd avA=(mh0,k0)@nx + bvA=(k0)@nx
      PH16(1, avB, bvB, avA, bvA, 1, Anx, Bnx, 0, 0, , );
    }
  } else {
    bf16x8 avA[4], avB[4], bvA[2], bvB[2];
    // Prologue: stage tile 0 fully (6 loads); retire + globalize; read p0 ops.
    stageA_k(&lA[0][0], in, b, h0, 0, 0, tid);
    stageB8_k(&lB[0][0], wts, nb, 0, 0, tid);
    stageA_k(&lA[0][0], in, b, h0, 0, 1, tid);
    stageB8_k(&lB[0][0], wts, nb, 0, 1, tid);
    __syncthreads();
#pragma unroll
    for (int m4_=0;m4_<4;++m4_)
      avA[m4_] = *(const bf16x8*)(&lA[0][0] + (((wm*8 + m4_)*4 + quad)*16 + l15)*8);
#pragma unroll
    for (int ni_=0;ni_<2;++ni_)
      bvA[ni_] = *(const bf16x8*)(&lB[0][0] + (((wn*2 + ni_)*4 + quad)*16 + l15)*8);

#pragma unroll 1
    for (int t = 0; t < 72; ++t){
      int d = t & 1;
      const u16* Acur = &lA[d][0];
      const u16* Bcur = &lB[d][0];
      u16* Anx = &lA[d^1][0];
      u16* Bnx = &lB[d^1][0];
      bool hn = (t < 71);
      int kn = t + 1;
      // p0: MFMA(avA,bvA)->(mh0,k0); rd avB=(mh1,k0)@cur; stage ALL 6 -> nx
      PH8Q(0, avA, bvA, avB, bvB, 0, Acur, Bcur, 1, 0,
           if (hn){ stageA_k(Anx, in, b, h0, kn, 0, tid);
                    stageB8_k(Bnx, wts, nb, kn, 0, tid);
                    stageA_k(Anx, in, b, h0, kn, 1, tid);
                    stageB8_k(Bnx, wts, nb, kn, 1, tid); }, );
      // p1: MFMA(avB,bvA)->(mh1,k0); rd avA=(mh0,k1)@cur + bvB=(k1)@cur
      PH8Q(1, avB, bvA, avA, bvB, 1, Acur, Bcur, 0, 1, , );
      // p2: MFMA(avA,bvB)->(mh0,k1); rd avB=(mh1,k1)@cur; then K-tile sync
      PH8Q(0, avA, bvB, avB, bvA, 0, Acur, Bcur, 1, 1, , SYNCTILE);
      // p3: MFMA(avB,bvB)->(mh1,k1); rd avA=(mh0,k0)@nx + bvA=(k0)@nx
      PH8Q(1, avB, bvB, avA, bvA, 1, Anx, Bnx, 0, 0, , );
    }
  }

  float bvl[NI];
#pragma unroll
  for (int ni = 0; ni < NI; ++ni)
    bvl[ni] = bias[nb*(NT*16) + wn*(NI*16) + ni*16 + l15];
  float sc = 0.f, ss = 0.f, sq = 0.f;
#pragma unroll
  for (int mi=0; mi<8; ++mi){
#pragma unroll
    for (int ni=0; ni<NI; ++ni){
      int n = nb*(NT*16) + wn*(NI*16) + ni*16 + l15;
#pragma unroll
      for (int r=0; r<4; ++r){
        int m = wm*128 + mi*16 + quad*4 + r;
        int row = h0 + (m >> 6), w = m & 63;
        float v = acc[mi][ni][r] + bvl[ni];
        v = fmaxf(v, 0.f);
        outp[(((b*64 + row)*64) + w)*(NT*32) + n] = f2bf(v);
        if (STATS){ sc += (v > 0.f) ? 1.f : 0.f; ss += v; sq += v*v; }
      }
    }
  }
  if constexpr (STATS){
    __shared__ float red[8][3];
#pragma unroll
    for (int off = 32; off; off >>= 1){
      sc += __shfl_down(sc, off); ss += __shfl_down(ss, off); sq += __shfl_down(sq, off);
    }
    if (lane == 0){ red[wave][0]=sc; red[wave][1]=ss; red[wave][2]=sq; }
    __syncthreads();
    if (tid == 0){
      float a0=0,a1=0,a2=0;
      for (int w2=0; w2<8; ++w2){ a0+=red[w2][0]; a1+=red[w2][1]; a2+=red[w2][2]; }
      partials[work*3+0]=a0; partials[work*3+1]=a1; partials[work*3+2]=a2;
    }
  }
}

// ---------------------------------------------------------------------------
// Reduce 256 per-work partials; work<128 -> update, else reset.
__global__ __launch_bounds__(256) void k_finalize(const float* __restrict__ partials,
                                                  float* __restrict__ ubs){
  __shared__ float red[4][6];
  int tid = threadIdx.x, lane = tid & 63, wave = tid >> 6;
  float cu=0,su=0,qu=0,cr=0,sr=0,qr=0;
  {
    float c = partials[tid*3+0], s = partials[tid*3+1], q = partials[tid*3+2];
    if (tid < 128){ cu=c; su=s; qu=q; } else { cr=c; sr=s; qr=q; }
  }
#pragma unroll
  for (int off = 32; off; off >>= 1){
    cu += __shfl_down(cu, off); su += __shfl_down(su, off); qu += __shfl_down(qu, off);
    cr += __shfl_down(cr, off); sr += __shfl_down(sr, off); qr += __shfl_down(qr, off);
  }
  if (lane == 0){ red[wave][0]=cu; red[wave][1]=su; red[wave][2]=qu;
                  red[wave][3]=cr; red[wave][4]=sr; red[wave][5]=qr; }
  __syncthreads();
  if (tid < 2){
    double C=0, S=0, Q=0;
    for (int w2=0; w2<4; ++w2){
      C += red[w2][tid*3+0]; S += red[w2][tid*3+1]; Q += red[w2][tid*3+2];
    }
    float ub = 1.f;
    if (C >= 2.0){
      double mean = S / C;
      double var = (Q - C*mean*mean) / (C - 1.0);
      if (var < 0.0) var = 0.0;
      ub = (float)(mean + 3.0*sqrt(var));
    }
    ubs[tid] = ub;
    ubs[2+tid] = 1.f/ub;
  }
}

// stacked2[...,256:512] = bf16(in_state * min(reset,ub_r)/ub_r)
__global__ __launch_bounds__(256) void k_mulreset(const u16* __restrict__ G,
    const u16* __restrict__ x2pad, const float* __restrict__ ubs,
    u16* __restrict__ stacked2){
  int tid = threadIdx.x, bh = blockIdx.x;
  int b = bh >> 6, h = bh & 63;
  int px = tid >> 2, cg = tid & 3;
  float ubr = ubs[1], inv = ubs[3];
#pragma unroll
  for (int u = 0; u < 8; ++u){
    int c = cg*64 + u*8;
    int4 gv = *(const int4*)(G + (bh*64 + px)*512 + 256 + c);
    int4 sv = *(const int4*)(x2pad + (((b*72 + h+4)*72) + (px+4))*256 + c);
    float gf[8], sf[8]; unpack8(gv, gf); unpack8(sv, sf);
    union { u16 h2[8]; int4 v; } R;
#pragma unroll
    for (int j=0;j<8;j++){
      float r = fminf(gf[j], ubr) * inv;
      R.h2[j] = f2bf(sf[j] * r);
    }
    *(int4*)(stacked2 + (((b*66 + h+1)*66) + (px+1))*512 + 256 + c) = R.v;
  }
}

// new_state = s*(1-u) + o*u, NCHW fp32 out (x2 copies), via LDS transpose.
__global__ __launch_bounds__(256) void k_final(const u16* __restrict__ G,
    const u16* __restrict__ O, const float* __restrict__ in_state,
    const float* __restrict__ ubs, float* __restrict__ dout){
  __shared__ float Q[64*65];
  __shared__ float P[64*65];
  int tid = threadIdx.x, bh = blockIdx.x;
  int b = bh >> 6, h = bh & 63;
  float ubu = ubs[0], inv = ubs[2];
  int px = tid >> 2, cs = (tid & 3)*16;
  int w = tid & 63, c4 = tid >> 6;
  for (int cb = 0; cb < 4; ++cb){
#pragma unroll
    for (int tt = 0; tt < 2; ++tt){
      int cl = cs + tt*8;
      int c = cb*64 + cl;
      int4 gv = *(const int4*)(G + (bh*64 + px)*512 + c);
      int4 ov = *(const int4*)(O + (bh*64 + px)*256 + c);
      float gf[8], of[8]; unpack8(gv, gf); unpack8(ov, of);
#pragma unroll
      for (int j=0;j<8;j++){
        float u = fminf(gf[j], ubu) * inv;
        Q[px*65 + cl + j] = u;
        P[px*65 + cl + j] = of[j]*u;
      }
    }
    __syncthreads();
    for (int i = 0; i < 16; ++i){
      int cl = i*4 + c4;
      int c = cb*64 + cl;
      int gidx = (((b*256 + c)*64) + h)*64 + w;
      float s = in_state[gidx];
      float v = s*(1.f - Q[w*65 + cl]) + P[w*65 + cl];
      dout[gidx] = v;
      dout[8388608 + gidx] = v;
    }
    __syncthreads();
  }
}

// ---------------------------------------------------------------------------
extern "C" void kernel_launch(void* const* d_in, const int* in_sizes, int n_in,
                              void* d_out, int out_size, void* d_ws, size_t ws_size,
                              hipStream_t stream){
  (void)in_sizes; (void)n_in; (void)out_size; (void)ws_size;
  const float* inputs   = (const float*)d_in[0];
  const float* in_state = (const float*)d_in[1];
  const float* w_reset  = (const float*)d_in[2];
  const float* b_reset  = (const float*)d_in[3];
  const float* w_update = (const float*)d_in[4];
  const float* b_update = (const float*)d_in[5];
  const float* w_out    = (const float*)d_in[6];
  const float* b_out    = (const float*)d_in[7];
  const float* w_offset = (const float*)d_in[8];
  const float* w_align  = (const float*)d_in[9];
  float* dout = (float*)d_out;

  char* ws = (char*)d_ws;
  size_t off = 0;
  auto alloc = [&](size_t bytes)->char*{
    char* p = ws + off; off = (off + bytes + 255) & ~(size_t)255; return p;
  };
  const size_t x2pad_b   = 8ull*72*72*256*2;
  const size_t stacked_b = 8ull*66*66*512*2;
  u16* x2pad    = (u16*)alloc(x2pad_b);
  u16* stacked  = (u16*)alloc(stacked_b);
  u16* stacked2 = (u16*)alloc(stacked_b);
  float* corr   = (float*)alloc(8ull*64*64*81*4);
  float* offs   = (float*)alloc(8ull*64*64*18*4);
  u16* G        = (u16*)alloc(8ull*64*64*512*2);
  u16* O        = (u16*)alloc(8ull*64*64*256*2);
  u16* wgate    = (u16*)alloc(512ull*4608*2);
  u16* woutb    = (u16*)alloc(256ull*4608*2);
  u16* walignb  = (u16*)alloc(256ull*2304*2);
  float* woff   = (float*)alloc(1458*4);
  float* biascat= (float*)alloc(512*4);
  float* partials=(float*)alloc(1024*3*4);
  float* ubs    = (float*)alloc(4*4);

  hipMemsetAsync(x2pad,    0, x2pad_b,   stream);
  hipMemsetAsync(stacked,  0, stacked_b, stream);
  hipMemsetAsync(stacked2, 0, stacked_b, stream);

  k_repack<<<9216, 256, 0, stream>>>(w_reset, b_reset, w_update, b_update, w_out,
                                     w_offset, w_align, wgate, woutb, walignb, woff, biascat);
  k_transform<<<512, 256, 0, stream>>>(inputs, in_state, stacked, stacked2, x2pad);
  k_corr<<<512, 256, 0, stream>>>(stacked, x2pad, corr);
  k_offset<<<1024, 256, 0, stream>>>(corr, woff, offs);
  k_deform<<<512, 256, 0, stream>>>(x2pad, offs, walignb, stacked);
  k_conv256<16, true><<<256, 512, 0, stream>>>(stacked, wgate, biascat, G, partials);
  k_finalize<<<1, 256, 0, stream>>>(partials, ubs);
  k_mulreset<<<512, 256, 0, stream>>>(G, x2pad, ubs, stacked2);
  k_conv256<8, false><<<256, 512, 0, stream>>>(stacked2, woutb, b_out, O, nullptr);
  k_final<<<512, 256, 0, stream>>>(G, O, in_state, ubs, dout);
}

// Round 7
// 631.870 us; speedup vs baseline: 1.0565x; 1.0565x over previous
//
#include <hip/hip_runtime.h>
#include <stdint.h>
#include <math.h>

typedef unsigned short u16;
typedef short bf16x8 __attribute__((ext_vector_type(8)));
typedef float f32x4 __attribute__((ext_vector_type(4)));

#define MFMA16x16x32(a,b,c) __builtin_amdgcn_mfma_f32_16x16x32_bf16((a),(b),(c),0,0,0)

typedef __attribute__((address_space(3))) void as3_void;
typedef const __attribute__((address_space(1))) void as1_void;

__device__ __forceinline__ void g2l16(const void* g, void* l){
#if __has_builtin(__builtin_amdgcn_global_load_lds)
  __builtin_amdgcn_global_load_lds((as1_void*)g, (as3_void*)l, 16, 0, 0);
#else
  *(int4*)l = *(const int4*)g;
#endif
}

__device__ __forceinline__ u16 f2bf(float f){
  uint32_t u = __builtin_bit_cast(uint32_t, f);
  u += 0x7fffu + ((u >> 16) & 1u);
  return (u16)(u >> 16);
}
__device__ __forceinline__ float bf2f(u16 h){
  uint32_t u = ((uint32_t)h) << 16;
  return __builtin_bit_cast(float, u);
}
__device__ __forceinline__ void unpack8(int4 v, float* o){
  uint32_t w0=(uint32_t)v.x, w1=(uint32_t)v.y, w2=(uint32_t)v.z, w3=(uint32_t)v.w;
  o[0]=__builtin_bit_cast(float, w0<<16); o[1]=__builtin_bit_cast(float, w0&0xffff0000u);
  o[2]=__builtin_bit_cast(float, w1<<16); o[3]=__builtin_bit_cast(float, w1&0xffff0000u);
  o[4]=__builtin_bit_cast(float, w2<<16); o[5]=__builtin_bit_cast(float, w2&0xffff0000u);
  o[6]=__builtin_bit_cast(float, w3<<16); o[7]=__builtin_bit_cast(float, w3&0xffff0000u);
}
__device__ __forceinline__ int iclampi(int v,int lo,int hi){ return v<lo?lo:(v>hi?hi:v); }

// ---------------------------------------------------------------------------
// Weights frag-packed per K-tile-64 chunk (identical layout to round 6).
__global__ void k_repack(const float* __restrict__ w_reset, const float* __restrict__ b_reset,
                         const float* __restrict__ w_update, const float* __restrict__ b_update,
                         const float* __restrict__ w_out, const float* __restrict__ w_offset,
                         const float* __restrict__ w_align,
                         u16* __restrict__ wgate, u16* __restrict__ wout,
                         u16* __restrict__ walign, float* __restrict__ woff,
                         float* __restrict__ biascat){
  int idx = blockIdx.x * 256 + threadIdx.x;
  if (idx < 512*4608){           // gate: BN=256, nb in {0,1}
    int e = idx & 7, j = (idx >> 3) & 2047, chunk = idx >> 14;
    int nb = chunk & 1, kk = chunk >> 1;
    int l = j & 15, q = (j >> 4) & 3, t16 = (j >> 6) & 15, ks2 = j >> 10;
    int n = nb*256 + t16*16 + l;
    int tap = kk >> 3, ksin = kk & 7;
    int c = ksin*64 + ks2*32 + q*8 + e;
    int ky = tap/3, kx = tap%3;
    float v = (n < 256) ? w_update[((n*512 + c)*3 + ky)*3 + kx]
                        : w_reset[(((n-256)*512 + c)*3 + ky)*3 + kx];
    wgate[idx] = f2bf(v);
  }
  if (idx < 256*4608){           // out: BN=128, nb in {0,1}
    int e = idx & 7, j = (idx >> 3) & 1023, chunk = idx >> 13;
    int nb = chunk & 1, kk = chunk >> 1;
    int l = j & 15, q = (j >> 4) & 3, t8 = (j >> 6) & 7, ks2 = j >> 9;
    int n = nb*128 + t8*16 + l;
    int tap = kk >> 3, ksin = kk & 7;
    int c = ksin*64 + ks2*32 + q*8 + e;
    int ky = tap/3, kx = tap%3;
    wout[idx] = f2bf(w_out[((n*512 + c)*3 + ky)*3 + kx]);
  }
  if (idx < 256*2304){           // align (k_deform reads directly)
    int n = idx / 2304, k = idx % 2304;
    int tap = k >> 8, c = k & 255;
    int ky = tap/3, kx = tap%3;
    walign[idx] = f2bf(w_align[((n*256 + c)*3 + ky)*3 + kx]);
  }
  if (idx < 1458) woff[idx] = w_offset[idx] * (1.f/256.f);
  if (idx < 512) biascat[idx] = (idx < 256) ? b_update[idx] : b_reset[idx-256];
}

// ---------------------------------------------------------------------------
// NCHW fp32 -> NHWC bf16.
__global__ __launch_bounds__(256) void k_transform(const float* __restrict__ inputs,
    const float* __restrict__ in_state, u16* __restrict__ stacked,
    u16* __restrict__ stacked2, u16* __restrict__ x2pad){
  __shared__ u16 t1[64*264];
  __shared__ u16 t2[64*264];
  int tid = threadIdx.x, bh = blockIdx.x;
  int b = bh >> 6, h = bh & 63;
  int w = tid & 63, cq = tid >> 6;
  for (int i = 0; i < 64; ++i){
    int c = i*4 + cq;
    int gi = ((b*256 + c)*64 + h)*64 + w;
    t1[w*264 + c] = f2bf(inputs[gi]);
    t2[w*264 + c] = f2bf(in_state[gi]);
  }
  __syncthreads();
  int px = tid >> 2, cg = tid & 3;
#pragma unroll
  for (int u = 0; u < 8; ++u){
    int c = cg*64 + u*8;
    int4 v1 = *(const int4*)(t1 + px*264 + c);
    int4 v2 = *(const int4*)(t2 + px*264 + c);
    *(int4*)(stacked  + (((b*66 + h+1)*66) + (px+1))*512 + c) = v1;
    *(int4*)(stacked2 + (((b*66 + h+1)*66) + (px+1))*512 + c) = v1;
    *(int4*)(x2pad    + (((b*72 + h+4)*72) + (px+4))*256 + c) = v2;
  }
}

// ---------------------------------------------------------------------------
// Correlation as masked local GEMM.
__global__ __launch_bounds__(256) void k_corr(const u16* __restrict__ stacked,
    const u16* __restrict__ x2pad, float* __restrict__ corr){
  __shared__ u16 lA[8192];
  __shared__ u16 lB[32768];
  int tid = threadIdx.x, idx = blockIdx.x;
  int b = idx >> 6, ty = (idx >> 3) & 7, tx = idx & 7;
  int h0 = ty*8, w0 = tx*8;
  int wave = tid >> 6, lane = tid & 63, l15 = lane & 15, quad = lane >> 4;
  f32x4 acc[4][4];
#pragma unroll
  for (int i=0;i<4;i++)
#pragma unroll
    for (int j=0;j<4;j++){ f32x4 z = {0.f,0.f,0.f,0.f}; acc[i][j] = z; }

  for (int s = 0; s < 2; ++s){
#pragma unroll
    for (int i = 0; i < 4; ++i){
      int j = tid + i*256;
      int ml = j & 15, q = (j>>4)&3, mt = (j>>6)&3, ks = j >> 8;
      int px = mt*16 + ml, py = px >> 3, pxx = px & 7;
      const u16* g = stacked + (((b*66 + h0+py+1)*66) + (w0+pxx+1))*512 + s*128 + ks*32 + q*8;
      g2l16(g, lA + j*8);
    }
#pragma unroll
    for (int i = 0; i < 16; ++i){
      int j = tid + i*256;
      int nl = j & 15, q = (j>>4)&3, nt = (j>>6)&15, ks = j >> 10;
      int qp = nt*16 + nl, qy = qp >> 4, qx = qp & 15;
      const u16* g = x2pad + (((b*72 + h0+qy)*72) + (w0+qx))*256 + s*128 + ks*32 + q*8;
      g2l16(g, lB + j*8);
    }
    __syncthreads();
#pragma unroll
    for (int ks = 0; ks < 4; ++ks){
      bf16x8 bv[4];
#pragma unroll
      for (int ni=0; ni<4; ++ni){
        int nt = wave*4 + ni;
        bv[ni] = *(const bf16x8*)(lB + (((ks*16 + nt)*4 + quad)*16 + l15)*8);
      }
#pragma unroll
      for (int mi=0; mi<4; ++mi){
        bf16x8 av = *(const bf16x8*)(lA + (((ks*4 + mi)*4 + quad)*16 + l15)*8);
#pragma unroll
        for (int ni=0; ni<4; ++ni) acc[mi][ni] = MFMA16x16x32(av, bv[ni], acc[mi][ni]);
      }
    }
    __syncthreads();
  }
#pragma unroll
  for (int mi=0; mi<4; ++mi){
#pragma unroll
    for (int ni=0; ni<4; ++ni){
      int n = wave*64 + ni*16 + l15;
      int qy = n >> 4, qx = n & 15;
#pragma unroll
      for (int r=0; r<4; ++r){
        int m = mi*16 + quad*4 + r;
        int py = m >> 3, pxx = m & 7;
        int dy = qy - py, dx = qx - pxx;
        if ((unsigned)dy <= 8u && (unsigned)dx <= 8u)
          corr[(((b*64 + h0+py)*64) + (w0+pxx))*81 + dy*9 + dx] = acc[mi][ni][r];
      }
    }
  }
}

// ---------------------------------------------------------------------------
__global__ __launch_bounds__(256) void k_offset(const float* __restrict__ corr,
    const float* __restrict__ woff, float* __restrict__ offs){
  __shared__ float lc[32*84];
  __shared__ float lw[18*84];
  int tid = threadIdx.x, blk = blockIdx.x;
  int row = blk >> 1, half = blk & 1;
  int base = row*5184 + half*32*81;
  for (int i = tid; i < 32*81; i += 256){
    int px = i / 81, d = i % 81;
    lc[px*84 + d] = corr[base + i];
  }
  for (int i = tid; i < 18*84; i += 256){
    int o = i / 84, d = i % 84;
    if (d < 81) lw[i] = woff[o*81 + d];
  }
  __syncthreads();
  int px = tid & 31, og = tid >> 5;
  for (int o = og; o < 18; o += 8){
    float s = 0.f;
#pragma unroll
    for (int dd = 0; dd < 20; ++dd){
      float4 a = *(const float4*)(lc + px*84 + dd*4);
      float4 wv = *(const float4*)(lw + o*84 + dd*4);
      s += a.x*wv.x + a.y*wv.y + a.z*wv.z + a.w*wv.w;
    }
    s += lc[px*84 + 80] * lw[o*84 + 80];
    offs[(row*64 + half*32 + px)*18 + o] = s;
  }
}

// ---------------------------------------------------------------------------
// Deformable conv (unchanged).
__global__ __launch_bounds__(256) void k_deform(const u16* __restrict__ x2pad,
    const float* __restrict__ offs, const u16* __restrict__ walign,
    u16* __restrict__ stacked){
  __shared__ u16 lA[16384];
  int tid = threadIdx.x, bh = blockIdx.x;
  int b = bh >> 6, h = bh & 63;
  int wave = tid >> 6, lane = tid & 63, l15 = lane & 15, quad = lane >> 4;
  int px = tid >> 2, cg = tid & 3;
  int mt_s = px >> 4, ml_s = px & 15;
  f32x4 acc[4][4];
#pragma unroll
  for (int i=0;i<4;i++)
#pragma unroll
    for (int j=0;j<4;j++){ f32x4 z = {0.f,0.f,0.f,0.f}; acc[i][j] = z; }

  for (int tap = 0; tap < 9; ++tap){
    int ky = tap/3, kx = tap%3;
    float offy = offs[(bh*64 + px)*18 + 2*tap];
    float offx = offs[(bh*64 + px)*18 + 2*tap + 1];
    float y = (float)(h + ky - 1) + offy;
    float x = (float)(px + kx - 1) + offx;
    float y0f = floorf(y), x0f = floorf(x);
    float wy1 = y - y0f, wx1 = x - x0f;
    float wy0 = 1.f - wy1, wx0 = 1.f - wx1;
    int iy0 = iclampi((int)y0f, -4, 67), ix0 = iclampi((int)x0f, -4, 67);
    int iy1 = iclampi((int)y0f + 1, -4, 67), ix1 = iclampi((int)x0f + 1, -4, 67);
    const u16* p00 = x2pad + (((b*72 + iy0+4)*72) + (ix0+4))*256 + cg*64;
    const u16* p01 = x2pad + (((b*72 + iy0+4)*72) + (ix1+4))*256 + cg*64;
    const u16* p10 = x2pad + (((b*72 + iy1+4)*72) + (ix0+4))*256 + cg*64;
    const u16* p11 = x2pad + (((b*72 + iy1+4)*72) + (ix1+4))*256 + cg*64;
    float w00 = wy0*wx0, w01 = wy0*wx1, w10 = wy1*wx0, w11 = wy1*wx1;
#pragma unroll
    for (int u = 0; u < 8; ++u){
      int4 v00 = *(const int4*)(p00 + u*8);
      int4 v01 = *(const int4*)(p01 + u*8);
      int4 v10 = *(const int4*)(p10 + u*8);
      int4 v11 = *(const int4*)(p11 + u*8);
      float a00[8], a01[8], a10[8], a11[8];
      unpack8(v00,a00); unpack8(v01,a01); unpack8(v10,a10); unpack8(v11,a11);
      union { u16 h2[8]; int4 v; } R;
#pragma unroll
      for (int jj = 0; jj < 8; ++jj)
        R.h2[jj] = f2bf(w00*a00[jj] + w01*a01[jj] + w10*a10[jj] + w11*a11[jj]);
      int ch = cg*64 + u*8;
      int ks = ch >> 5, q = (ch >> 3) & 3;
      *(int4*)(lA + (((ks*4 + mt_s)*4 + q)*16 + ml_s)*8) = R.v;
    }
    __syncthreads();
#pragma unroll
    for (int ks = 0; ks < 8; ++ks){
      bf16x8 bv[4];
#pragma unroll
      for (int ni=0; ni<4; ++ni){
        int n = wave*64 + ni*16 + l15;
        bv[ni] = *(const bf16x8*)(walign + n*2304 + tap*256 + ks*32 + quad*8);
      }
#pragma unroll
      for (int mi=0; mi<4; ++mi){
        bf16x8 av = *(const bf16x8*)(lA + (((ks*4 + mi)*4 + quad)*16 + l15)*8);
#pragma unroll
        for (int ni=0; ni<4; ++ni) acc[mi][ni] = MFMA16x16x32(av, bv[ni], acc[mi][ni]);
      }
    }
    __syncthreads();
  }
#pragma unroll
  for (int mi=0; mi<4; ++mi){
#pragma unroll
    for (int ni=0; ni<4; ++ni){
      int n = wave*64 + ni*16 + l15;
#pragma unroll
      for (int r=0; r<4; ++r){
        int m = mi*16 + quad*4 + r;
        stacked[(((b*66 + h+1)*66) + (m+1))*512 + 256 + n] = f2bf(acc[mi][ni][r]);
      }
    }
  }
}

// ---------------------------------------------------------------------------
// A-staging, COALESCED: LDS is pixel-major [256 px][64 ch] (32 KB), dest
// linear (slot j = i*512+tid -> wave-uniform base + lane*16, g2l16-legal).
// Slot j holds global 16B chunk c8 = (j&7) ^ (px&7) of pixel px = j>>3 —
// 8 consecutive lanes consume ONE full 128B line (XOR permutes within the
// line; still single-line coalesced). 8x less L2 traffic than the old
// 1KB-stride scatter. Reads undo the XOR (rule #21: both sides or neither).
__device__ __forceinline__ void stageA_cl(u16* __restrict__ dst,
    const u16* __restrict__ in, int b, int h0, int kk, int tid){
  int tap = kk >> 3, ksin = kk & 7;
  int ky = tap/3, kx = tap - ky*3;
  const u16* abase = in + ((b*66 + h0 + ky)*66 + kx)*512 + ksin*64;
#pragma unroll
  for (int i = 0; i < 4; ++i){
    int j = i*512 + tid;
    int px = j >> 3, i8 = j & 7;
    int c8 = i8 ^ (px & 7);
    int r = px >> 6, w = px & 63;
    g2l16(abase + (r*66 + w)*512 + c8*8, dst + j*8);
  }
}
__device__ __forceinline__ void stageB16_k(u16* __restrict__ dst,
    const u16* __restrict__ wts, int nb, int kk, int ks2, int tid){
  const u16* wch = wts + (size_t)(kk*2 + nb) * 16384;
#pragma unroll
  for (int i = 0; i < 2; ++i){
    int j = (ks2<<10) | (i<<9) | tid;
    g2l16(wch + j*8, dst + j*8);
  }
}
__device__ __forceinline__ void stageB8_k(u16* __restrict__ dst,
    const u16* __restrict__ wts, int nb, int kk, int ks2, int tid){
  const u16* wch = wts + (size_t)(kk*2 + nb) * 8192;
  int j = (ks2<<9) | tid;
  g2l16(wch + j*8, dst + j*8);
}

// A-fragment read from pixel-major XOR-swizzled LDS: lane (quad,l15) wants
// pixel px = mrow*16 + l15, channels ks2*32 + quad*8 (16B). Chunk index
// (ks2*4+quad) XOR'd with px&7 == l15&7. Bank math: px*128 aliases all rows
// to the same banks; the XOR spreads the 16 l15-rows across all 8 16B
// columns -> b128 services at the 8-cycle minimum (no excess conflict).
#define AVREAD(RA, MROW, K2) \
  (*(const bf16x8*)((const u16*)(RA) + (MROW)*1024 + l15*64 + \
    ((((K2)*32) + quad*8) ^ ((l15 & 7)*8))))

// ---------------------------------------------------------------------------
// Phase skeleton (round 6 schedule, unchanged): next-phase operand ds_reads,
// staging at p0, fenced MFMA cluster; ONE __syncthreads per K-tile (end-p2).
#define PH16(CMH, AVC, BVC, AVN, BVN, LOADB, RA, RB, NMH, NK2, STG, EPI) do { \
  _Pragma("unroll") \
  for (int m4_=0;m4_<4;++m4_) \
    AVN[m4_] = AVREAD(RA, wm*8 + (NMH)*4 + m4_, NK2); \
  if (LOADB){ \
    _Pragma("unroll") \
    for (int ni_=0;ni_<4;++ni_) \
      BVN[ni_] = *(const bf16x8*)((const u16*)(RB) + ((((NK2)*16 + wn*4 + ni_)*4 + quad)*16 + l15)*8); \
  } \
  STG; \
  __builtin_amdgcn_sched_barrier(0); \
  __builtin_amdgcn_s_setprio(1); \
  _Pragma("unroll") \
  for (int m4_=0;m4_<4;++m4_){ \
    _Pragma("unroll") \
    for (int ni_=0;ni_<4;++ni_) \
      acc[(CMH)*4+m4_][ni_] = MFMA16x16x32(AVC[m4_], BVC[ni_], acc[(CMH)*4+m4_][ni_]); \
  } \
  __builtin_amdgcn_s_setprio(0); \
  __builtin_amdgcn_sched_barrier(0); \
  EPI; \
} while(0)

// NT=8 quarter-phase: 4 av x 2 bv = 8 MFMA.
#define PH8Q(CMH, AVC, BVC, AVN, BVN, LOADB, RA, RB, NMH, NK2, STG, EPI) do { \
  _Pragma("unroll") \
  for (int m4_=0;m4_<4;++m4_) \
    AVN[m4_] = AVREAD(RA, wm*8 + (NMH)*4 + m4_, NK2); \
  if (LOADB){ \
    _Pragma("unroll") \
    for (int ni_=0;ni_<2;++ni_) \
      BVN[ni_] = *(const bf16x8*)((const u16*)(RB) + ((((NK2)*8 + wn*2 + ni_)*4 + quad)*16 + l15)*8); \
  } \
  STG; \
  __builtin_amdgcn_sched_barrier(0); \
  __builtin_amdgcn_s_setprio(1); \
  _Pragma("unroll") \
  for (int m4_=0;m4_<4;++m4_){ \
    _Pragma("unroll") \
    for (int ni_=0;ni_<2;++ni_) \
      acc[(CMH)*4+m4_][ni_] = MFMA16x16x32(AVC[m4_], BVC[ni_], acc[(CMH)*4+m4_][ni_]); \
  } \
  __builtin_amdgcn_s_setprio(0); \
  __builtin_amdgcn_sched_barrier(0); \
  EPI; \
} while(0)

#define SYNCTILE do { \
  __syncthreads(); \
  __builtin_amdgcn_sched_barrier(0); \
} while(0)

// 3x3 conv, implicit GEMM, 256px x (NT*16)n tile, 8 waves (2M x 4N), BK=64.
// One-phase register lookahead + ONE barrier per K-tile + coalesced A-stage.
template<int NT, bool STATS>
__global__ __launch_bounds__(512, 2) void k_conv256(const u16* __restrict__ in,
    const u16* __restrict__ wts, const float* __restrict__ bias,
    u16* __restrict__ outp, float* __restrict__ partials){
  constexpr int NI = NT / 4;
  __shared__ u16 lA[2][16384];      // 256 px x 64 ch per buffer, pixel-major
  __shared__ u16 lB[2][NT*1024];    // (NT*16) n x 64 ch per buffer, frag-packed

  int tid = threadIdx.x, g = blockIdx.x;
  int work = (g & 7) * 32 + (g >> 3);     // bijective XCD swizzle (256 % 8 == 0)
  int nb = work >> 7, mt = work & 127;    // nb-major: 32 works/XCD share B panel
  int b = mt >> 4, h0 = (mt & 15) * 4;
  int wave = tid >> 6, lane = tid & 63, l15 = lane & 15, quad = lane >> 4;
  int wm = wave & 1, wn = wave >> 1;

  f32x4 acc[8][NI];
#pragma unroll
  for (int i=0;i<8;i++)
#pragma unroll
    for (int j=0;j<NI;j++){ f32x4 z = {0.f,0.f,0.f,0.f}; acc[i][j] = z; }

  if constexpr (NT == 16){
    bf16x8 avA[4], avB[4], bvA[4], bvB[4];
    // Prologue: stage tile 0 fully; retire + globalize; read p0 operands.
    stageA_cl(&lA[0][0], in, b, h0, 0, tid);
    stageB16_k(&lB[0][0], wts, nb, 0, 0, tid);
    stageB16_k(&lB[0][0], wts, nb, 0, 1, tid);
    __syncthreads();
#pragma unroll
    for (int m4_=0;m4_<4;++m4_)
      avA[m4_] = AVREAD(&lA[0][0], wm*8 + m4_, 0);
#pragma unroll
    for (int ni_=0;ni_<4;++ni_)
      bvA[ni_] = *(const bf16x8*)(&lB[0][0] + (((wn*4 + ni_)*4 + quad)*16 + l15)*8);

#pragma unroll 1
    for (int t = 0; t < 72; ++t){
      int d = t & 1;
      const u16* Acur = &lA[d][0];
      const u16* Bcur = &lB[d][0];
      u16* Anx = &lA[d^1][0];
      u16* Bnx = &lB[d^1][0];
      bool hn = (t < 71);
      int kn = t + 1;
      // p0: MFMA(avA,bvA)->(mh0,k0); rd avB=(mh1,k0)@cur; stage ALL 8 -> nx
      PH16(0, avA, bvA, avB, bvB, 0, Acur, Bcur, 1, 0,
           if (hn){ stageA_cl(Anx, in, b, h0, kn, tid);
                    stageB16_k(Bnx, wts, nb, kn, 0, tid);
                    stageB16_k(Bnx, wts, nb, kn, 1, tid); }, );
      // p1: MFMA(avB,bvA)->(mh1,k0); rd avA=(mh0,k1)@cur + bvB=(k1)@cur
      PH16(1, avB, bvA, avA, bvB, 1, Acur, Bcur, 0, 1, , );
      // p2: MFMA(avA,bvB)->(mh0,k1); rd avB=(mh1,k1)@cur; then K-tile sync
      PH16(0, avA, bvB, avB, bvA, 0, Acur, Bcur, 1, 1, , SYNCTILE);
      // p3: MFMA(avB,bvB)->(mh1,k1); rd avA=(mh0,k0)@nx + bvA=(k0)@nx
      PH16(1, avB, bvB, avA, bvA, 1, Anx, Bnx, 0, 0, , );
    }
  } else {
    bf16x8 avA[4], avB[4], bvA[2], bvB[2];
    // Prologue: stage tile 0 fully (6 loads); retire + globalize; read p0 ops.
    stageA_cl(&lA[0][0], in, b, h0, 0, tid);
    stageB8_k(&lB[0][0], wts, nb, 0, 0, tid);
    stageB8_k(&lB[0][0], wts, nb, 0, 1, tid);
    __syncthreads();
#pragma unroll
    for (int m4_=0;m4_<4;++m4_)
      avA[m4_] = AVREAD(&lA[0][0], wm*8 + m4_, 0);
#pragma unroll
    for (int ni_=0;ni_<2;++ni_)
      bvA[ni_] = *(const bf16x8*)(&lB[0][0] + (((wn*2 + ni_)*4 + quad)*16 + l15)*8);

#pragma unroll 1
    for (int t = 0; t < 72; ++t){
      int d = t & 1;
      const u16* Acur = &lA[d][0];
      const u16* Bcur = &lB[d][0];
      u16* Anx = &lA[d^1][0];
      u16* Bnx = &lB[d^1][0];
      bool hn = (t < 71);
      int kn = t + 1;
      // p0: MFMA(avA,bvA)->(mh0,k0); rd avB=(mh1,k0)@cur; stage ALL 6 -> nx
      PH8Q(0, avA, bvA, avB, bvB, 0, Acur, Bcur, 1, 0,
           if (hn){ stageA_cl(Anx, in, b, h0, kn, tid);
                    stageB8_k(Bnx, wts, nb, kn, 0, tid);
                    stageB8_k(Bnx, wts, nb, kn, 1, tid); }, );
      // p1: MFMA(avB,bvA)->(mh1,k0); rd avA=(mh0,k1)@cur + bvB=(k1)@cur
      PH8Q(1, avB, bvA, avA, bvB, 1, Acur, Bcur, 0, 1, , );
      // p2: MFMA(avA,bvB)->(mh0,k1); rd avB=(mh1,k1)@cur; then K-tile sync
      PH8Q(0, avA, bvB, avB, bvA, 0, Acur, Bcur, 1, 1, , SYNCTILE);
      // p3: MFMA(avB,bvB)->(mh1,k1); rd avA=(mh0,k0)@nx + bvA=(k0)@nx
      PH8Q(1, avB, bvB, avA, bvA, 1, Anx, Bnx, 0, 0, , );
    }
  }

  float bvl[NI];
#pragma unroll
  for (int ni = 0; ni < NI; ++ni)
    bvl[ni] = bias[nb*(NT*16) + wn*(NI*16) + ni*16 + l15];
  float sc = 0.f, ss = 0.f, sq = 0.f;
#pragma unroll
  for (int mi=0; mi<8; ++mi){
#pragma unroll
    for (int ni=0; ni<NI; ++ni){
      int n = nb*(NT*16) + wn*(NI*16) + ni*16 + l15;
#pragma unroll
      for (int r=0; r<4; ++r){
        int m = wm*128 + mi*16 + quad*4 + r;
        int row = h0 + (m >> 6), w = m & 63;
        float v = acc[mi][ni][r] + bvl[ni];
        v = fmaxf(v, 0.f);
        outp[(((b*64 + row)*64) + w)*(NT*32) + n] = f2bf(v);
        if (STATS){ sc += (v > 0.f) ? 1.f : 0.f; ss += v; sq += v*v; }
      }
    }
  }
  if constexpr (STATS){
    __shared__ float red[8][3];
#pragma unroll
    for (int off = 32; off; off >>= 1){
      sc += __shfl_down(sc, off); ss += __shfl_down(ss, off); sq += __shfl_down(sq, off);
    }
    if (lane == 0){ red[wave][0]=sc; red[wave][1]=ss; red[wave][2]=sq; }
    __syncthreads();
    if (tid == 0){
      float a0=0,a1=0,a2=0;
      for (int w2=0; w2<8; ++w2){ a0+=red[w2][0]; a1+=red[w2][1]; a2+=red[w2][2]; }
      partials[work*3+0]=a0; partials[work*3+1]=a1; partials[work*3+2]=a2;
    }
  }
}

// ---------------------------------------------------------------------------
// Reduce 256 per-work partials; work<128 -> update, else reset.
__global__ __launch_bounds__(256) void k_finalize(const float* __restrict__ partials,
                                                  float* __restrict__ ubs){
  __shared__ float red[4][6];
  int tid = threadIdx.x, lane = tid & 63, wave = tid >> 6;
  float cu=0,su=0,qu=0,cr=0,sr=0,qr=0;
  {
    float c = partials[tid*3+0], s = partials[tid*3+1], q = partials[tid*3+2];
    if (tid < 128){ cu=c; su=s; qu=q; } else { cr=c; sr=s; qr=q; }
  }
#pragma unroll
  for (int off = 32; off; off >>= 1){
    cu += __shfl_down(cu, off); su += __shfl_down(su, off); qu += __shfl_down(qu, off);
    cr += __shfl_down(cr, off); sr += __shfl_down(sr, off); qr += __shfl_down(qr, off);
  }
  if (lane == 0){ red[wave][0]=cu; red[wave][1]=su; red[wave][2]=qu;
                  red[wave][3]=cr; red[wave][4]=sr; red[wave][5]=qr; }
  __syncthreads();
  if (tid < 2){
    double C=0, S=0, Q=0;
    for (int w2=0; w2<4; ++w2){
      C += red[w2][tid*3+0]; S += red[w2][tid*3+1]; Q += red[w2][tid*3+2];
    }
    float ub = 1.f;
    if (C >= 2.0){
      double mean = S / C;
      double var = (Q - C*mean*mean) / (C - 1.0);
      if (var < 0.0) var = 0.0;
      ub = (float)(mean + 3.0*sqrt(var));
    }
    ubs[tid] = ub;
    ubs[2+tid] = 1.f/ub;
  }
}

// stacked2[...,256:512] = bf16(in_state * min(reset,ub_r)/ub_r)
__global__ __launch_bounds__(256) void k_mulreset(const u16* __restrict__ G,
    const u16* __restrict__ x2pad, const float* __restrict__ ubs,
    u16* __restrict__ stacked2){
  int tid = threadIdx.x, bh = blockIdx.x;
  int b = bh >> 6, h = bh & 63;
  int px = tid >> 2, cg = tid & 3;
  float ubr = ubs[1], inv = ubs[3];
#pragma unroll
  for (int u = 0; u < 8; ++u){
    int c = cg*64 + u*8;
    int4 gv = *(const int4*)(G + (bh*64 + px)*512 + 256 + c);
    int4 sv = *(const int4*)(x2pad + (((b*72 + h+4)*72) + (px+4))*256 + c);
    float gf[8], sf[8]; unpack8(gv, gf); unpack8(sv, sf);
    union { u16 h2[8]; int4 v; } R;
#pragma unroll
    for (int j=0;j<8;j++){
      float r = fminf(gf[j], ubr) * inv;
      R.h2[j] = f2bf(sf[j] * r);
    }
    *(int4*)(stacked2 + (((b*66 + h+1)*66) + (px+1))*512 + 256 + c) = R.v;
  }
}

// new_state = s*(1-u) + o*u, NCHW fp32 out (x2 copies), via LDS transpose.
__global__ __launch_bounds__(256) void k_final(const u16* __restrict__ G,
    const u16* __restrict__ O, const float* __restrict__ in_state,
    const float* __restrict__ ubs, float* __restrict__ dout){
  __shared__ float Q[64*65];
  __shared__ float P[64*65];
  int tid = threadIdx.x, bh = blockIdx.x;
  int b = bh >> 6, h = bh & 63;
  float ubu = ubs[0], inv = ubs[2];
  int px = tid >> 2, cs = (tid & 3)*16;
  int w = tid & 63, c4 = tid >> 6;
  for (int cb = 0; cb < 4; ++cb){
#pragma unroll
    for (int tt = 0; tt < 2; ++tt){
      int cl = cs + tt*8;
      int c = cb*64 + cl;
      int4 gv = *(const int4*)(G + (bh*64 + px)*512 + c);
      int4 ov = *(const int4*)(O + (bh*64 + px)*256 + c);
      float gf[8], of[8]; unpack8(gv, gf); unpack8(ov, of);
#pragma unroll
      for (int j=0;j<8;j++){
        float u = fminf(gf[j], ubu) * inv;
        Q[px*65 + cl + j] = u;
        P[px*65 + cl + j] = of[j]*u;
      }
    }
    __syncthreads();
    for (int i = 0; i < 16; ++i){
      int cl = i*4 + c4;
      int c = cb*64 + cl;
      int gidx = (((b*256 + c)*64) + h)*64 + w;
      float s = in_state[gidx];
      float v = s*(1.f - Q[w*65 + cl]) + P[w*65 + cl];
      dout[gidx] = v;
      dout[8388608 + gidx] = v;
    }
    __syncthreads();
  }
}

// ---------------------------------------------------------------------------
extern "C" void kernel_launch(void* const* d_in, const int* in_sizes, int n_in,
                              void* d_out, int out_size, void* d_ws, size_t ws_size,
                              hipStream_t stream){
  (void)in_sizes; (void)n_in; (void)out_size; (void)ws_size;
  const float* inputs   = (const float*)d_in[0];
  const float* in_state = (const float*)d_in[1];
  const float* w_reset  = (const float*)d_in[2];
  const float* b_reset  = (const float*)d_in[3];
  const float* w_update = (const float*)d_in[4];
  const float* b_update = (const float*)d_in[5];
  const float* w_out    = (const float*)d_in[6];
  const float* b_out    = (const float*)d_in[7];
  const float* w_offset = (const float*)d_in[8];
  const float* w_align  = (const float*)d_in[9];
  float* dout = (float*)d_out;

  char* ws = (char*)d_ws;
  size_t off = 0;
  auto alloc = [&](size_t bytes)->char*{
    char* p = ws + off; off = (off + bytes + 255) & ~(size_t)255; return p;
  };
  const size_t x2pad_b   = 8ull*72*72*256*2;
  const size_t stacked_b = 8ull*66*66*512*2;
  u16* x2pad    = (u16*)alloc(x2pad_b);
  u16* stacked  = (u16*)alloc(stacked_b);
  u16* stacked2 = (u16*)alloc(stacked_b);
  float* corr   = (float*)alloc(8ull*64*64*81*4);
  float* offs   = (float*)alloc(8ull*64*64*18*4);
  u16* G        = (u16*)alloc(8ull*64*64*512*2);
  u16* O        = (u16*)alloc(8ull*64*64*256*2);
  u16* wgate    = (u16*)alloc(512ull*4608*2);
  u16* woutb    = (u16*)alloc(256ull*4608*2);
  u16* walignb  = (u16*)alloc(256ull*2304*2);
  float* woff   = (float*)alloc(1458*4);
  float* biascat= (float*)alloc(512*4);
  float* partials=(float*)alloc(1024*3*4);
  float* ubs    = (float*)alloc(4*4);

  hipMemsetAsync(x2pad,    0, x2pad_b,   stream);
  hipMemsetAsync(stacked,  0, stacked_b, stream);
  hipMemsetAsync(stacked2, 0, stacked_b, stream);

  k_repack<<<9216, 256, 0, stream>>>(w_reset, b_reset, w_update, b_update, w_out,
                                     w_offset, w_align, wgate, woutb, walignb, woff, biascat);
  k_transform<<<512, 256, 0, stream>>>(inputs, in_state, stacked, stacked2, x2pad);
  k_corr<<<512, 256, 0, stream>>>(stacked, x2pad, corr);
  k_offset<<<1024, 256, 0, stream>>>(corr, woff, offs);
  k_deform<<<512, 256, 0, stream>>>(x2pad, offs, walignb, stacked);
  k_conv256<16, true><<<256, 512, 0, stream>>>(stacked, wgate, biascat, G, partials);
  k_finalize<<<1, 256, 0, stream>>>(partials, ubs);
  k_mulreset<<<512, 256, 0, stream>>>(G, x2pad, ubs, stacked2);
  k_conv256<8, false><<<256, 512, 0, stream>>>(stacked2, woutb, b_out, O, nullptr);
  k_final<<<512, 256, 0, stream>>>(G, O, in_state, ubs, dout);
}

// Round 9
// 568.820 us; speedup vs baseline: 1.1736x; 1.1108x over previous
//
#include <hip/hip_runtime.h>
#include <stdint.h>
#include <math.h>

typedef unsigned short u16;
typedef short bf16x8 __attribute__((ext_vector_type(8)));
typedef float f32x4 __attribute__((ext_vector_type(4)));

#define MFMA16x16x32(a,b,c) __builtin_amdgcn_mfma_f32_16x16x32_bf16((a),(b),(c),0,0,0)

typedef __attribute__((address_space(3))) void as3_void;
typedef const __attribute__((address_space(1))) void as1_void;

__device__ __forceinline__ void g2l16(const void* g, void* l){
#if __has_builtin(__builtin_amdgcn_global_load_lds)
  __builtin_amdgcn_global_load_lds((as1_void*)g, (as3_void*)l, 16, 0, 0);
#else
  *(int4*)l = *(const int4*)g;
#endif
}

__device__ __forceinline__ u16 f2bf(float f){
  uint32_t u = __builtin_bit_cast(uint32_t, f);
  u += 0x7fffu + ((u >> 16) & 1u);
  return (u16)(u >> 16);
}
__device__ __forceinline__ float bf2f(u16 h){
  uint32_t u = ((uint32_t)h) << 16;
  return __builtin_bit_cast(float, u);
}
__device__ __forceinline__ void unpack8(int4 v, float* o){
  uint32_t w0=(uint32_t)v.x, w1=(uint32_t)v.y, w2=(uint32_t)v.z, w3=(uint32_t)v.w;
  o[0]=__builtin_bit_cast(float, w0<<16); o[1]=__builtin_bit_cast(float, w0&0xffff0000u);
  o[2]=__builtin_bit_cast(float, w1<<16); o[3]=__builtin_bit_cast(float, w1&0xffff0000u);
  o[4]=__builtin_bit_cast(float, w2<<16); o[5]=__builtin_bit_cast(float, w2&0xffff0000u);
  o[6]=__builtin_bit_cast(float, w3<<16); o[7]=__builtin_bit_cast(float, w3&0xffff0000u);
}
__device__ __forceinline__ int iclampi(int v,int lo,int hi){ return v<lo?lo:(v>hi?hi:v); }

// ---------------------------------------------------------------------------
// Weights frag-packed. Gate/out layouts as round 7. walign layout:
// (tap,ks)-major so deform's bv reads are lane-contiguous 1KB:
// idx = u*8192 + n*32 + quad*8 + e, u = tap*8+ks, c = ks*32+quad*8+e.
__global__ void k_repack(const float* __restrict__ w_reset, const float* __restrict__ b_reset,
                         const float* __restrict__ w_update, const float* __restrict__ b_update,
                         const float* __restrict__ w_out, const float* __restrict__ w_offset,
                         const float* __restrict__ w_align,
                         u16* __restrict__ wgate, u16* __restrict__ wout,
                         u16* __restrict__ walign, float* __restrict__ woff,
                         float* __restrict__ biascat){
  int idx = blockIdx.x * 256 + threadIdx.x;
  if (idx < 512*4608){           // gate: BN=256, nb in {0,1}
    int e = idx & 7, j = (idx >> 3) & 2047, chunk = idx >> 14;
    int nb = chunk & 1, kk = chunk >> 1;
    int l = j & 15, q = (j >> 4) & 3, t16 = (j >> 6) & 15, ks2 = j >> 10;
    int n = nb*256 + t16*16 + l;
    int tap = kk >> 3, ksin = kk & 7;
    int c = ksin*64 + ks2*32 + q*8 + e;
    int ky = tap/3, kx = tap%3;
    float v = (n < 256) ? w_update[((n*512 + c)*3 + ky)*3 + kx]
                        : w_reset[(((n-256)*512 + c)*3 + ky)*3 + kx];
    wgate[idx] = f2bf(v);
  }
  if (idx < 256*4608){           // out: BN=128, nb in {0,1}
    int e = idx & 7, j = (idx >> 3) & 1023, chunk = idx >> 13;
    int nb = chunk & 1, kk = chunk >> 1;
    int l = j & 15, q = (j >> 4) & 3, t8 = (j >> 6) & 7, ks2 = j >> 9;
    int n = nb*128 + t8*16 + l;
    int tap = kk >> 3, ksin = kk & 7;
    int c = ksin*64 + ks2*32 + q*8 + e;
    int ky = tap/3, kx = tap%3;
    wout[idx] = f2bf(w_out[((n*512 + c)*3 + ky)*3 + kx]);
  }
  if (idx < 256*2304){           // align: (tap,ks)-major for coalesced bv reads
    int u = idx >> 13, rem = idx & 8191;
    int n = rem >> 5, qd = (rem >> 3) & 3, e = idx & 7;
    int tap = u >> 3, ks = u & 7;
    int c = ks*32 + qd*8 + e;
    int ky = tap/3, kx = tap%3;
    walign[idx] = f2bf(w_align[((n*256 + c)*3 + ky)*3 + kx]);
  }
  if (idx < 1458) woff[idx] = w_offset[idx] * (1.f/256.f);
  if (idx < 512) biascat[idx] = (idx < 256) ? b_update[idx] : b_reset[idx-256];
}

// ---------------------------------------------------------------------------
// NCHW fp32 -> NHWC bf16.
__global__ __launch_bounds__(256) void k_transform(const float* __restrict__ inputs,
    const float* __restrict__ in_state, u16* __restrict__ stacked,
    u16* __restrict__ stacked2, u16* __restrict__ x2pad){
  __shared__ u16 t1[64*264];
  __shared__ u16 t2[64*264];
  int tid = threadIdx.x, bh = blockIdx.x;
  int b = bh >> 6, h = bh & 63;
  int w = tid & 63, cq = tid >> 6;
  for (int i = 0; i < 64; ++i){
    int c = i*4 + cq;
    int gi = ((b*256 + c)*64 + h)*64 + w;
    t1[w*264 + c] = f2bf(inputs[gi]);
    t2[w*264 + c] = f2bf(in_state[gi]);
  }
  __syncthreads();
  int px = tid >> 2, cg = tid & 3;
#pragma unroll
  for (int u = 0; u < 8; ++u){
    int c = cg*64 + u*8;
    int4 v1 = *(const int4*)(t1 + px*264 + c);
    int4 v2 = *(const int4*)(t2 + px*264 + c);
    *(int4*)(stacked  + (((b*66 + h+1)*66) + (px+1))*512 + c) = v1;
    *(int4*)(stacked2 + (((b*66 + h+1)*66) + (px+1))*512 + c) = v1;
    *(int4*)(x2pad    + (((b*72 + h+4)*72) + (px+4))*256 + c) = v2;
  }
}

// ---------------------------------------------------------------------------
// Correlation as masked local GEMM.
__global__ __launch_bounds__(256) void k_corr(const u16* __restrict__ stacked,
    const u16* __restrict__ x2pad, float* __restrict__ corr){
  __shared__ u16 lA[8192];
  __shared__ u16 lB[32768];
  int tid = threadIdx.x, idx = blockIdx.x;
  int b = idx >> 6, ty = (idx >> 3) & 7, tx = idx & 7;
  int h0 = ty*8, w0 = tx*8;
  int wave = tid >> 6, lane = tid & 63, l15 = lane & 15, quad = lane >> 4;
  f32x4 acc[4][4];
#pragma unroll
  for (int i=0;i<4;i++)
#pragma unroll
    for (int j=0;j<4;j++){ f32x4 z = {0.f,0.f,0.f,0.f}; acc[i][j] = z; }

  for (int s = 0; s < 2; ++s){
#pragma unroll
    for (int i = 0; i < 4; ++i){
      int j = tid + i*256;
      int ml = j & 15, q = (j>>4)&3, mt = (j>>6)&3, ks = j >> 8;
      int px = mt*16 + ml, py = px >> 3, pxx = px & 7;
      const u16* g = stacked + (((b*66 + h0+py+1)*66) + (w0+pxx+1))*512 + s*128 + ks*32 + q*8;
      g2l16(g, lA + j*8);
    }
#pragma unroll
    for (int i = 0; i < 16; ++i){
      int j = tid + i*256;
      int nl = j & 15, q = (j>>4)&3, nt = (j>>6)&15, ks = j >> 10;
      int qp = nt*16 + nl, qy = qp >> 4, qx = qp & 15;
      const u16* g = x2pad + (((b*72 + h0+qy)*72) + (w0+qx))*256 + s*128 + ks*32 + q*8;
      g2l16(g, lB + j*8);
    }
    __syncthreads();
#pragma unroll
    for (int ks = 0; ks < 4; ++ks){
      bf16x8 bv[4];
#pragma unroll
      for (int ni=0; ni<4; ++ni){
        int nt = wave*4 + ni;
        bv[ni] = *(const bf16x8*)(lB + (((ks*16 + nt)*4 + quad)*16 + l15)*8);
      }
#pragma unroll
      for (int mi=0; mi<4; ++mi){
        bf16x8 av = *(const bf16x8*)(lA + (((ks*4 + mi)*4 + quad)*16 + l15)*8);
#pragma unroll
        for (int ni=0; ni<4; ++ni) acc[mi][ni] = MFMA16x16x32(av, bv[ni], acc[mi][ni]);
      }
    }
    __syncthreads();
  }
#pragma unroll
  for (int mi=0; mi<4; ++mi){
#pragma unroll
    for (int ni=0; ni<4; ++ni){
      int n = wave*64 + ni*16 + l15;
      int qy = n >> 4, qx = n & 15;
#pragma unroll
      for (int r=0; r<4; ++r){
        int m = mi*16 + quad*4 + r;
        int py = m >> 3, pxx = m & 7;
        int dy = qy - py, dx = qx - pxx;
        if ((unsigned)dy <= 8u && (unsigned)dx <= 8u)
          corr[(((b*64 + h0+py)*64) + (w0+pxx))*81 + dy*9 + dx] = acc[mi][ni][r];
      }
    }
  }
}

// ---------------------------------------------------------------------------
__global__ __launch_bounds__(256) void k_offset(const float* __restrict__ corr,
    const float* __restrict__ woff, float* __restrict__ offs){
  __shared__ float lc[32*84];
  __shared__ float lw[18*84];
  int tid = threadIdx.x, blk = blockIdx.x;
  int row = blk >> 1, half = blk & 1;
  int base = row*5184 + half*32*81;
  for (int i = tid; i < 32*81; i += 256){
    int px = i / 81, d = i % 81;
    lc[px*84 + d] = corr[base + i];
  }
  for (int i = tid; i < 18*84; i += 256){
    int o = i / 84, d = i % 84;
    if (d < 81) lw[i] = woff[o*81 + d];
  }
  __syncthreads();
  int px = tid & 31, og = tid >> 5;
  for (int o = og; o < 18; o += 8){
    float s = 0.f;
#pragma unroll
    for (int dd = 0; dd < 20; ++dd){
      float4 a = *(const float4*)(lc + px*84 + dd*4);
      float4 wv = *(const float4*)(lw + o*84 + dd*4);
      s += a.x*wv.x + a.y*wv.y + a.z*wv.z + a.w*wv.w;
    }
    s += lc[px*84 + 80] * lw[o*84 + 80];
    offs[(row*64 + half*32 + px)*18 + o] = s;
  }
}

// ---------------------------------------------------------------------------
// Deformable conv, v2: transaction-coalesced gather (32 lanes = one
// (pixel,corner)'s contiguous 512B -> 8 lines/wave-inst vs 64), XOR-swizzled
// frag writes (write ml^=c32&7 / read l15^=(ks*4+quad)&7 — verified
// round-trip identity), (tap,ks)-major walign (1KB lane-contiguous bv),
// double-buffered lA with ONE __syncthreads per tap (stage t+1 || MFMA t).
__global__ __launch_bounds__(256) void k_deform(const u16* __restrict__ x2pad,
    const float* __restrict__ offs, const u16* __restrict__ walign,
    u16* __restrict__ stacked){
  __shared__ u16 lA[2][16384];
  int tid = threadIdx.x, bh = blockIdx.x;
  int b = bh >> 6, h = bh & 63;
  int wave = tid >> 6, lane = tid & 63, l15 = lane & 15, quad = lane >> 4;
  int g8 = tid >> 5, c32 = tid & 31;
  int ksw = c32 >> 2, qw = c32 & 3, x7 = c32 & 7;
  f32x4 acc[4][4];
#pragma unroll
  for (int i=0;i<4;i++)
#pragma unroll
    for (int j=0;j<4;j++){ f32x4 z = {0.f,0.f,0.f,0.f}; acc[i][j] = z; }

  auto STAGE = [&](u16* __restrict__ dst, int tap){
    int ky = tap/3, kx = tap - ky*3;
#pragma unroll 2
    for (int pi = 0; pi < 8; ++pi){
      int px = pi*8 + g8;
      float offy = offs[(bh*64 + px)*18 + 2*tap];
      float offx = offs[(bh*64 + px)*18 + 2*tap + 1];
      float y = (float)(h + ky - 1) + offy;
      float x = (float)(px + kx - 1) + offx;
      float y0f = floorf(y), x0f = floorf(x);
      float wy1 = y - y0f, wx1 = x - x0f;
      float wy0 = 1.f - wy1, wx0 = 1.f - wx1;
      int iy0 = iclampi((int)y0f, -4, 67), ix0 = iclampi((int)x0f, -4, 67);
      int iy1 = iclampi((int)y0f + 1, -4, 67), ix1 = iclampi((int)x0f + 1, -4, 67);
      const u16* p00 = x2pad + (((b*72 + iy0+4)*72) + (ix0+4))*256 + c32*8;
      const u16* p01 = x2pad + (((b*72 + iy0+4)*72) + (ix1+4))*256 + c32*8;
      const u16* p10 = x2pad + (((b*72 + iy1+4)*72) + (ix0+4))*256 + c32*8;
      const u16* p11 = x2pad + (((b*72 + iy1+4)*72) + (ix1+4))*256 + c32*8;
      int4 v00 = *(const int4*)p00;
      int4 v01 = *(const int4*)p01;
      int4 v10 = *(const int4*)p10;
      int4 v11 = *(const int4*)p11;
      float w00 = wy0*wx0, w01 = wy0*wx1, w10 = wy1*wx0, w11 = wy1*wx1;
      float a00[8], a01[8], a10[8], a11[8];
      unpack8(v00,a00); unpack8(v01,a01); unpack8(v10,a10); unpack8(v11,a11);
      union { u16 h2[8]; int4 v; } R;
#pragma unroll
      for (int jj = 0; jj < 8; ++jj)
        R.h2[jj] = f2bf(w00*a00[jj] + w01*a01[jj] + w10*a10[jj] + w11*a11[jj]);
      int mt = px >> 4, ml = px & 15;
      *(int4*)(dst + ksw*2048 + mt*512 + qw*128 + (ml ^ x7)*8) = R.v;
    }
  };

  STAGE(&lA[0][0], 0);
  __syncthreads();

  for (int tap = 0; tap < 9; ++tap){
    int d = tap & 1;
    if (tap < 8) STAGE(&lA[d^1][0], tap + 1);
    const u16* A = &lA[d][0];
    __builtin_amdgcn_s_setprio(1);
#pragma unroll
    for (int ks = 0; ks < 8; ++ks){
      bf16x8 bv[4];
#pragma unroll
      for (int ni=0; ni<4; ++ni){
        int n = wave*64 + ni*16 + l15;
        bv[ni] = *(const bf16x8*)(walign + (size_t)(tap*8 + ks)*8192 + n*32 + quad*8);
      }
#pragma unroll
      for (int mi=0; mi<4; ++mi){
        bf16x8 av = *(const bf16x8*)(A + ks*2048 + mi*512 + quad*128 + (l15 ^ ((ks*4 + quad) & 7))*8);
#pragma unroll
        for (int ni=0; ni<4; ++ni) acc[mi][ni] = MFMA16x16x32(av, bv[ni], acc[mi][ni]);
      }
    }
    __builtin_amdgcn_s_setprio(0);
    __syncthreads();
  }
#pragma unroll
  for (int mi=0; mi<4; ++mi){
#pragma unroll
    for (int ni=0; ni<4; ++ni){
      int n = wave*64 + ni*16 + l15;
#pragma unroll
      for (int r=0; r<4; ++r){
        int m = mi*16 + quad*4 + r;
        stacked[(((b*66 + h+1)*66) + (m+1))*512 + 256 + n] = f2bf(acc[mi][ni][r]);
      }
    }
  }
}

// ---------------------------------------------------------------------------
// A-staging, COALESCED (round 7, unchanged).
__device__ __forceinline__ void stageA_cl(u16* __restrict__ dst,
    const u16* __restrict__ in, int b, int h0, int kk, int tid){
  int tap = kk >> 3, ksin = kk & 7;
  int ky = tap/3, kx = tap - ky*3;
  const u16* abase = in + ((b*66 + h0 + ky)*66 + kx)*512 + ksin*64;
#pragma unroll
  for (int i = 0; i < 4; ++i){
    int j = i*512 + tid;
    int px = j >> 3, i8 = j & 7;
    int c8 = i8 ^ (px & 7);
    int r = px >> 6, w = px & 63;
    g2l16(abase + (r*66 + w)*512 + c8*8, dst + j*8);
  }
}
__device__ __forceinline__ void stageB16_k(u16* __restrict__ dst,
    const u16* __restrict__ wts, int nb, int kk, int ks2, int tid){
  const u16* wch = wts + (size_t)(kk*2 + nb) * 16384;
#pragma unroll
  for (int i = 0; i < 2; ++i){
    int j = (ks2<<10) | (i<<9) | tid;
    g2l16(wch + j*8, dst + j*8);
  }
}
__device__ __forceinline__ void stageB8_k(u16* __restrict__ dst,
    const u16* __restrict__ wts, int nb, int kk, int ks2, int tid){
  const u16* wch = wts + (size_t)(kk*2 + nb) * 8192;
  int j = (ks2<<9) | tid;
  g2l16(wch + j*8, dst + j*8);
}

#define AVREAD(RA, MROW, K2) \
  (*(const bf16x8*)((const u16*)(RA) + (MROW)*1024 + l15*64 + \
    ((((K2)*32) + quad*8) ^ ((l15 & 7)*8))))

// ---------------------------------------------------------------------------
// Conv phase skeleton (round 7, unchanged).
#define PH16(CMH, AVC, BVC, AVN, BVN, LOADB, RA, RB, NMH, NK2, STG, EPI) do { \
  _Pragma("unroll") \
  for (int m4_=0;m4_<4;++m4_) \
    AVN[m4_] = AVREAD(RA, wm*8 + (NMH)*4 + m4_, NK2); \
  if (LOADB){ \
    _Pragma("unroll") \
    for (int ni_=0;ni_<4;++ni_) \
      BVN[ni_] = *(const bf16x8*)((const u16*)(RB) + ((((NK2)*16 + wn*4 + ni_)*4 + quad)*16 + l15)*8); \
  } \
  STG; \
  __builtin_amdgcn_sched_barrier(0); \
  __builtin_amdgcn_s_setprio(1); \
  _Pragma("unroll") \
  for (int m4_=0;m4_<4;++m4_){ \
    _Pragma("unroll") \
    for (int ni_=0;ni_<4;++ni_) \
      acc[(CMH)*4+m4_][ni_] = MFMA16x16x32(AVC[m4_], BVC[ni_], acc[(CMH)*4+m4_][ni_]); \
  } \
  __builtin_amdgcn_s_setprio(0); \
  __builtin_amdgcn_sched_barrier(0); \
  EPI; \
} while(0)

#define PH8Q(CMH, AVC, BVC, AVN, BVN, LOADB, RA, RB, NMH, NK2, STG, EPI) do { \
  _Pragma("unroll") \
  for (int m4_=0;m4_<4;++m4_) \
    AVN[m4_] = AVREAD(RA, wm*8 + (NMH)*4 + m4_, NK2); \
  if (LOADB){ \
    _Pragma("unroll") \
    for (int ni_=0;ni_<2;++ni_) \
      BVN[ni_] = *(const bf16x8*)((const u16*)(RB) + ((((NK2)*8 + wn*2 + ni_)*4 + quad)*16 + l15)*8); \
  } \
  STG; \
  __builtin_amdgcn_sched_barrier(0); \
  __builtin_amdgcn_s_setprio(1); \
  _Pragma("unroll") \
  for (int m4_=0;m4_<4;++m4_){ \
    _Pragma("unroll") \
    for (int ni_=0;ni_<2;++ni_) \
      acc[(CMH)*4+m4_][ni_] = MFMA16x16x32(AVC[m4_], BVC[ni_], acc[(CMH)*4+m4_][ni_]); \
  } \
  __builtin_amdgcn_s_setprio(0); \
  __builtin_amdgcn_sched_barrier(0); \
  EPI; \
} while(0)

#define SYNCTILE do { \
  __syncthreads(); \
  __builtin_amdgcn_sched_barrier(0); \
} while(0)

template<int NT, bool STATS>
__global__ __launch_bounds__(512, 2) void k_conv256(const u16* __restrict__ in,
    const u16* __restrict__ wts, const float* __restrict__ bias,
    u16* __restrict__ outp, float* __restrict__ partials){
  constexpr int NI = NT / 4;
  __shared__ u16 lA[2][16384];
  __shared__ u16 lB[2][NT*1024];

  int tid = threadIdx.x, g = blockIdx.x;
  int work = (g & 7) * 32 + (g >> 3);
  int nb = work >> 7, mt = work & 127;
  int b = mt >> 4, h0 = (mt & 15) * 4;
  int wave = tid >> 6, lane = tid & 63, l15 = lane & 15, quad = lane >> 4;
  int wm = wave & 1, wn = wave >> 1;

  f32x4 acc[8][NI];
#pragma unroll
  for (int i=0;i<8;i++)
#pragma unroll
    for (int j=0;j<NI;j++){ f32x4 z = {0.f,0.f,0.f,0.f}; acc[i][j] = z; }

  if constexpr (NT == 16){
    bf16x8 avA[4], avB[4], bvA[4], bvB[4];
    stageA_cl(&lA[0][0], in, b, h0, 0, tid);
    stageB16_k(&lB[0][0], wts, nb, 0, 0, tid);
    stageB16_k(&lB[0][0], wts, nb, 0, 1, tid);
    __syncthreads();
#pragma unroll
    for (int m4_=0;m4_<4;++m4_)
      avA[m4_] = AVREAD(&lA[0][0], wm*8 + m4_, 0);
#pragma unroll
    for (int ni_=0;ni_<4;++ni_)
      bvA[ni_] = *(const bf16x8*)(&lB[0][0] + (((wn*4 + ni_)*4 + quad)*16 + l15)*8);

#pragma unroll 1
    for (int t = 0; t < 72; ++t){
      int d = t & 1;
      const u16* Acur = &lA[d][0];
      const u16* Bcur = &lB[d][0];
      u16* Anx = &lA[d^1][0];
      u16* Bnx = &lB[d^1][0];
      bool hn = (t < 71);
      int kn = t + 1;
      PH16(0, avA, bvA, avB, bvB, 0, Acur, Bcur, 1, 0,
           if (hn){ stageA_cl(Anx, in, b, h0, kn, tid);
                    stageB16_k(Bnx, wts, nb, kn, 0, tid);
                    stageB16_k(Bnx, wts, nb, kn, 1, tid); }, );
      PH16(1, avB, bvA, avA, bvB, 1, Acur, Bcur, 0, 1, , );
      PH16(0, avA, bvB, avB, bvA, 0, Acur, Bcur, 1, 1, , SYNCTILE);
      PH16(1, avB, bvB, avA, bvA, 1, Anx, Bnx, 0, 0, , );
    }
  } else {
    bf16x8 avA[4], avB[4], bvA[2], bvB[2];
    stageA_cl(&lA[0][0], in, b, h0, 0, tid);
    stageB8_k(&lB[0][0], wts, nb, 0, 0, tid);
    stageB8_k(&lB[0][0], wts, nb, 0, 1, tid);
    __syncthreads();
#pragma unroll
    for (int m4_=0;m4_<4;++m4_)
      avA[m4_] = AVREAD(&lA[0][0], wm*8 + m4_, 0);
#pragma unroll
    for (int ni_=0;ni_<2;++ni_)
      bvA[ni_] = *(const bf16x8*)(&lB[0][0] + (((wn*2 + ni_)*4 + quad)*16 + l15)*8);

#pragma unroll 1
    for (int t = 0; t < 72; ++t){
      int d = t & 1;
      const u16* Acur = &lA[d][0];
      const u16* Bcur = &lB[d][0];
      u16* Anx = &lA[d^1][0];
      u16* Bnx = &lB[d^1][0];
      bool hn = (t < 71);
      int kn = t + 1;
      PH8Q(0, avA, bvA, avB, bvB, 0, Acur, Bcur, 1, 0,
           if (hn){ stageA_cl(Anx, in, b, h0, kn, tid);
                    stageB8_k(Bnx, wts, nb, kn, 0, tid);
                    stageB8_k(Bnx, wts, nb, kn, 1, tid); }, );
      PH8Q(1, avB, bvA, avA, bvB, 1, Acur, Bcur, 0, 1, , );
      PH8Q(0, avA, bvB, avB, bvA, 0, Acur, Bcur, 1, 1, , SYNCTILE);
      PH8Q(1, avB, bvB, avA, bvA, 1, Anx, Bnx, 0, 0, , );
    }
  }

  float bvl[NI];
#pragma unroll
  for (int ni = 0; ni < NI; ++ni)
    bvl[ni] = bias[nb*(NT*16) + wn*(NI*16) + ni*16 + l15];
  float sc = 0.f, ss = 0.f, sq = 0.f;
#pragma unroll
  for (int mi=0; mi<8; ++mi){
#pragma unroll
    for (int ni=0; ni<NI; ++ni){
      int n = nb*(NT*16) + wn*(NI*16) + ni*16 + l15;
#pragma unroll
      for (int r=0; r<4; ++r){
        int m = wm*128 + mi*16 + quad*4 + r;
        int row = h0 + (m >> 6), w = m & 63;
        float v = acc[mi][ni][r] + bvl[ni];
        v = fmaxf(v, 0.f);
        outp[(((b*64 + row)*64) + w)*(NT*32) + n] = f2bf(v);
        if (STATS){ sc += (v > 0.f) ? 1.f : 0.f; ss += v; sq += v*v; }
      }
    }
  }
  if constexpr (STATS){
    __shared__ float red[8][3];
#pragma unroll
    for (int off = 32; off; off >>= 1){
      sc += __shfl_down(sc, off); ss += __shfl_down(ss, off); sq += __shfl_down(sq, off);
    }
    if (lane == 0){ red[wave][0]=sc; red[wave][1]=ss; red[wave][2]=sq; }
    __syncthreads();
    if (tid == 0){
      float a0=0,a1=0,a2=0;
      for (int w2=0; w2<8; ++w2){ a0+=red[w2][0]; a1+=red[w2][1]; a2+=red[w2][2]; }
      partials[work*3+0]=a0; partials[work*3+1]=a1; partials[work*3+2]=a2;
    }
  }
}

// ---------------------------------------------------------------------------
__global__ __launch_bounds__(256) void k_finalize(const float* __restrict__ partials,
                                                  float* __restrict__ ubs){
  __shared__ float red[4][6];
  int tid = threadIdx.x, lane = tid & 63, wave = tid >> 6;
  float cu=0,su=0,qu=0,cr=0,sr=0,qr=0;
  {
    float c = partials[tid*3+0], s = partials[tid*3+1], q = partials[tid*3+2];
    if (tid < 128){ cu=c; su=s; qu=q; } else { cr=c; sr=s; qr=q; }
  }
#pragma unroll
  for (int off = 32; off; off >>= 1){
    cu += __shfl_down(cu, off); su += __shfl_down(su, off); qu += __shfl_down(qu, off);
    cr += __shfl_down(cr, off); sr += __shfl_down(sr, off); qr += __shfl_down(qr, off);
  }
  if (lane == 0){ red[wave][0]=cu; red[wave][1]=su; red[wave][2]=qu;
                  red[wave][3]=cr; red[wave][4]=sr; red[wave][5]=qr; }
  __syncthreads();
  if (tid < 2){
    double C=0, S=0, Q=0;
    for (int w2=0; w2<4; ++w2){
      C += red[w2][tid*3+0]; S += red[w2][tid*3+1]; Q += red[w2][tid*3+2];
    }
    float ub = 1.f;
    if (C >= 2.0){
      double mean = S / C;
      double var = (Q - C*mean*mean) / (C - 1.0);
      if (var < 0.0) var = 0.0;
      ub = (float)(mean + 3.0*sqrt(var));
    }
    ubs[tid] = ub;
    ubs[2+tid] = 1.f/ub;
  }
}

// stacked2[...,256:512] = bf16(in_state * min(reset,ub_r)/ub_r)
__global__ __launch_bounds__(256) void k_mulreset(const u16* __restrict__ G,
    const u16* __restrict__ x2pad, const float* __restrict__ ubs,
    u16* __restrict__ stacked2){
  int tid = threadIdx.x, bh = blockIdx.x;
  int b = bh >> 6, h = bh & 63;
  int px = tid >> 2, cg = tid & 3;
  float ubr = ubs[1], inv = ubs[3];
#pragma unroll
  for (int u = 0; u < 8; ++u){
    int c = cg*64 + u*8;
    int4 gv = *(const int4*)(G + (bh*64 + px)*512 + 256 + c);
    int4 sv = *(const int4*)(x2pad + (((b*72 + h+4)*72) + (px+4))*256 + c);
    float gf[8], sf[8]; unpack8(gv, gf); unpack8(sv, sf);
    union { u16 h2[8]; int4 v; } R;
#pragma unroll
    for (int j=0;j<8;j++){
      float r = fminf(gf[j], ubr) * inv;
      R.h2[j] = f2bf(sf[j] * r);
    }
    *(int4*)(stacked2 + (((b*66 + h+1)*66) + (px+1))*512 + 256 + c) = R.v;
  }
}

// new_state = s*(1-u) + o*u, NCHW fp32 out (x2 copies), via LDS transpose.
__global__ __launch_bounds__(256) void k_final(const u16* __restrict__ G,
    const u16* __restrict__ O, const float* __restrict__ in_state,
    const float* __restrict__ ubs, float* __restrict__ dout){
  __shared__ float Q[64*65];
  __shared__ float P[64*65];
  int tid = threadIdx.x, bh = blockIdx.x;
  int b = bh >> 6, h = bh & 63;
  float ubu = ubs[0], inv = ubs[2];
  int px = tid >> 2, cs = (tid & 3)*16;
  int w = tid & 63, c4 = tid >> 6;
  for (int cb = 0; cb < 4; ++cb){
#pragma unroll
    for (int tt = 0; tt < 2; ++tt){
      int cl = cs + tt*8;
      int c = cb*64 + cl;
      int4 gv = *(const int4*)(G + (bh*64 + px)*512 + c);
      int4 ov = *(const int4*)(O + (bh*64 + px)*256 + c);
      float gf[8], of[8]; unpack8(gv, gf); unpack8(ov, of);
#pragma unroll
      for (int j=0;j<8;j++){
        float u = fminf(gf[j], ubu) * inv;
        Q[px*65 + cl + j] = u;
        P[px*65 + cl + j] = of[j]*u;
      }
    }
    __syncthreads();
    for (int i = 0; i < 16; ++i){
      int cl = i*4 + c4;
      int c = cb*64 + cl;
      int gidx = (((b*256 + c)*64) + h)*64 + w;
      float s = in_state[gidx];
      float v = s*(1.f - Q[w*65 + cl]) + P[w*65 + cl];
      dout[gidx] = v;
      dout[8388608 + gidx] = v;
    }
    __syncthreads();
  }
}

// ---------------------------------------------------------------------------
extern "C" void kernel_launch(void* const* d_in, const int* in_sizes, int n_in,
                              void* d_out, int out_size, void* d_ws, size_t ws_size,
                              hipStream_t stream){
  (void)in_sizes; (void)n_in; (void)out_size; (void)ws_size;
  const float* inputs   = (const float*)d_in[0];
  const float* in_state = (const float*)d_in[1];
  const float* w_reset  = (const float*)d_in[2];
  const float* b_reset  = (const float*)d_in[3];
  const float* w_update = (const float*)d_in[4];
  const float* b_update = (const float*)d_in[5];
  const float* w_out    = (const float*)d_in[6];
  const float* b_out    = (const float*)d_in[7];
  const float* w_offset = (const float*)d_in[8];
  const float* w_align  = (const float*)d_in[9];
  float* dout = (float*)d_out;

  char* ws = (char*)d_ws;
  size_t off = 0;
  auto alloc = [&](size_t bytes)->char*{
    char* p = ws + off; off = (off + bytes + 255) & ~(size_t)255; return p;
  };
  const size_t x2pad_b   = 8ull*72*72*256*2;
  const size_t stacked_b = 8ull*66*66*512*2;
  u16* x2pad    = (u16*)alloc(x2pad_b);
  u16* stacked  = (u16*)alloc(stacked_b);
  u16* stacked2 = (u16*)alloc(stacked_b);
  float* corr   = (float*)alloc(8ull*64*64*81*4);
  float* offs   = (float*)alloc(8ull*64*64*18*4);
  u16* G        = (u16*)alloc(8ull*64*64*512*2);
  u16* O        = (u16*)alloc(8ull*64*64*256*2);
  u16* wgate    = (u16*)alloc(512ull*4608*2);
  u16* woutb    = (u16*)alloc(256ull*4608*2);
  u16* walignb  = (u16*)alloc(256ull*2304*2);
  float* woff   = (float*)alloc(1458*4);
  float* biascat= (float*)alloc(512*4);
  float* partials=(float*)alloc(1024*3*4);
  float* ubs    = (float*)alloc(4*4);

  hipMemsetAsync(x2pad,    0, x2pad_b,   stream);
  hipMemsetAsync(stacked,  0, stacked_b, stream);
  hipMemsetAsync(stacked2, 0, stacked_b, stream);

  k_repack<<<9216, 256, 0, stream>>>(w_reset, b_reset, w_update, b_update, w_out,
                                     w_offset, w_align, wgate, woutb, walignb, woff, biascat);
  k_transform<<<512, 256, 0, stream>>>(inputs, in_state, stacked, stacked2, x2pad);
  k_corr<<<512, 256, 0, stream>>>(stacked, x2pad, corr);
  k_offset<<<1024, 256, 0, stream>>>(corr, woff, offs);
  k_deform<<<512, 256, 0, stream>>>(x2pad, offs, walignb, stacked);
  k_conv256<16, true><<<256, 512, 0, stream>>>(stacked, wgate, biascat, G, partials);
  k_finalize<<<1, 256, 0, stream>>>(partials, ubs);
  k_mulreset<<<512, 256, 0, stream>>>(G, x2pad, ubs, stacked2);
  k_conv256<8, false><<<256, 512, 0, stream>>>(stacked2, woutb, b_out, O, nullptr);
  k_final<<<512, 256, 0, stream>>>(G, O, in_state, ubs, dout);
}